// Round 11
// baseline (261.535 us; speedup 1.0000x reference)
//
#include <hip/hip_runtime.h>
#include <hip/hip_bf16.h>
#include <math.h>

// Problem constants (Mask2Former pixel decoder / MS-deformable attention)
#define BB 4
#define SEQ 5376
#define DD 256
#define NH 8
#define NL 3
#define NP 4
#define DH 32
#define MTOT (BB * SEQ)          // 21504 rows for all GEMMs

typedef __attribute__((ext_vector_type(8))) short bf16x8;
typedef __attribute__((ext_vector_type(4))) float f32x4;

__device__ __forceinline__ ushort f2b(float f) {
    __hip_bfloat16 h = __float2bfloat16(f);
    return *reinterpret_cast<ushort*>(&h);
}

// ---------------------------------------------------------------------------
// Fused prep: blocks [0,800] transpose weights -> Wt[800][256] bf16 (+bias
// combine at block 800); blocks [801, 801+2048) convert hidden -> bf16 and
// (hidden+pos) -> bf16 (grid-stride).
// ---------------------------------------------------------------------------
__global__ __launch_bounds__(256) void prep_all(
    const float* __restrict__ hidden, const float* __restrict__ pos,
    const float* __restrict__ Wv, const float* __restrict__ Wo,
    const float* __restrict__ Wa, const float* __restrict__ Wout,
    const float* __restrict__ bo, const float* __restrict__ ba,
    ushort4* __restrict__ hb, ushort4* __restrict__ hsb,
    ushort* __restrict__ Wt, float* __restrict__ bcomb, int n4) {
    int bid = blockIdx.x;
    int tid = threadIdx.x;
    if (bid <= 800) {
        if (bid == 800) {
            for (int i = tid; i < 288; i += 256)
                bcomb[i] = (i < 192) ? bo[i] : ba[i - 192];
            return;
        }
        int row = bid;
        const float* src;
        int N, n;
        if (row < 256)      { src = Wv;   N = 256; n = row; }
        else if (row < 448) { src = Wo;   N = 192; n = row - 256; }
        else if (row < 544) { src = Wa;   N = 96;  n = row - 448; }
        else                { src = Wout; N = 256; n = row - 544; }
        float v = src[(size_t)tid * N + n];
        Wt[(size_t)row * 256 + tid] = f2b(v);
        return;
    }
    // activation conversion
    const float4* h4 = (const float4*)hidden;
    const float4* p4 = (const float4*)pos;
    int i = (bid - 801) * 256 + tid;
    int stride = (gridDim.x - 801) * 256;
    for (; i < n4; i += stride) {
        float4 a = h4[i], b = p4[i];
        ushort4 ua, us;
        ua.x = f2b(a.x); ua.y = f2b(a.y); ua.z = f2b(a.z); ua.w = f2b(a.w);
        us.x = f2b(a.x + b.x); us.y = f2b(a.y + b.y);
        us.z = f2b(a.z + b.z); us.w = f2b(a.w + b.w);
        hb[i] = ua;
        hsb[i] = us;
    }
}

// ---------------------------------------------------------------------------
// bf16 MFMA GEMM: C[M,N] = A[M,K]@W[K,N] + bias  (A bf16 [M][K], Wt bf16 [N][K])
// BM=128, BN=128, BK=64. 256 threads = 4 waves 2x2; wave tile 64x64 via 4x4
// fragments of mfma_f32_16x16x32_bf16; 32 MFMA per wave per barrier pair.
// OBF: bf16 output, else fp32. N guarded.
// ---------------------------------------------------------------------------
template<bool OBF>
__global__ __launch_bounds__(256) void gemm_mfma(
    const ushort* __restrict__ A, const ushort* __restrict__ Wt,
    const float* __restrict__ bias, void* __restrict__ Cout,
    int M, int N, int K) {
    const int BM = 128, BN = 128, BK = 64, PK = 72;   // PK: padded LDS row
    __shared__ ushort As[BM][PK];
    __shared__ ushort Bs[BN][PK];
    int bm = blockIdx.y * BM;
    int bn = blockIdx.x * BN;
    int tid = threadIdx.x;
    int lane = tid & 63;
    int wid = tid >> 6;
    int wr = wid >> 1, wc = wid & 1;     // 2x2 wave grid
    int lr = lane & 15;                  // row-in-frag (A) / col (B,C)
    int kg = lane >> 4;                  // k-group 0..3

    f32x4 acc[4][4] = {};

    for (int k0 = 0; k0 < K; k0 += BK) {
        // stage A: 128 rows x 64 bf16 = 1024 chunks of 8 bf16 (16B)
        #pragma unroll
        for (int c = 0; c < 4; c++) {
            int e = tid + 256 * c;
            int row = e >> 3, q = e & 7;
            const ushort* src = A + (size_t)(bm + row) * K + k0 + 8 * q;
            *(bf16x8*)&As[row][8 * q] = *(const bf16x8*)src;
        }
        // stage B: 128 rows x 64 bf16 = 1024 chunks
        #pragma unroll
        for (int c = 0; c < 4; c++) {
            int e = tid + 256 * c;
            int row = e >> 3, q = e & 7;
            int gn = bn + row;
            bf16x8 v = {0, 0, 0, 0, 0, 0, 0, 0};
            if (gn < N) v = *(const bf16x8*)(Wt + (size_t)gn * K + k0 + 8 * q);
            *(bf16x8*)&Bs[row][8 * q] = v;
        }
        __syncthreads();
        #pragma unroll
        for (int ks = 0; ks < 2; ks++) {
            bf16x8 af[4], bfr[4];
            #pragma unroll
            for (int mf = 0; mf < 4; mf++)
                af[mf] = *(bf16x8*)&As[wr * 64 + mf * 16 + lr][ks * 32 + kg * 8];
            #pragma unroll
            for (int nf = 0; nf < 4; nf++)
                bfr[nf] = *(bf16x8*)&Bs[wc * 64 + nf * 16 + lr][ks * 32 + kg * 8];
            #pragma unroll
            for (int mf = 0; mf < 4; mf++)
                #pragma unroll
                for (int nf = 0; nf < 4; nf++)
                    acc[mf][nf] = __builtin_amdgcn_mfma_f32_16x16x32_bf16(
                        af[mf], bfr[nf], acc[mf][nf], 0, 0, 0);
        }
        __syncthreads();
    }

    // epilogue: C[row][col] = acc + bias[col]
    #pragma unroll
    for (int nf = 0; nf < 4; nf++) {
        int gc = bn + wc * 64 + nf * 16 + lr;
        if (gc >= N) continue;
        float bv = bias[gc];
        #pragma unroll
        for (int mf = 0; mf < 4; mf++) {
            int gr0 = bm + wr * 64 + mf * 16 + kg * 4;
            #pragma unroll
            for (int r = 0; r < 4; r++) {
                float v = acc[mf][nf][r] + bv;
                if constexpr (OBF)
                    ((ushort*)Cout)[(size_t)(gr0 + r) * N + gc] = f2b(v);
                else
                    ((float*)Cout)[(size_t)(gr0 + r) * N + gc] = v;
            }
        }
    }
}

// ---------------------------------------------------------------------------
// Deformable sampling v9: fused softmax + tap table + 16B gathers + 2-deep
// tap pipeline. Block = 128 threads (2 waves) = 4 queries (32 lanes/query).
// launch_bounds(128,5): <=102 VGPR so the pipeline regs don't kill occupancy.
// Phase 1: 512 slots = 4q x 8h x 16 lanes (lp<12 active); 16-lane shfl
//          softmax -> attn_out; tap idx/weights -> LDS.
// Phase 2: per lane 8 channels (16B); loads for tap lp+1 issued before FMAs
//          of tap lp (distinct registers -> 2 taps of loads in flight).
// ---------------------------------------------------------------------------
struct Acc8 {
    float a0, a1, a2, a3, a4, a5, a6, a7;
};

__device__ __forceinline__ void fma8(Acc8& acc, float wt, uint4 u) {
    acc.a0 = fmaf(wt, __uint_as_float(u.x << 16), acc.a0);
    acc.a1 = fmaf(wt, __uint_as_float(u.x & 0xffff0000u), acc.a1);
    acc.a2 = fmaf(wt, __uint_as_float(u.y << 16), acc.a2);
    acc.a3 = fmaf(wt, __uint_as_float(u.y & 0xffff0000u), acc.a3);
    acc.a4 = fmaf(wt, __uint_as_float(u.z << 16), acc.a4);
    acc.a5 = fmaf(wt, __uint_as_float(u.z & 0xffff0000u), acc.a5);
    acc.a6 = fmaf(wt, __uint_as_float(u.w << 16), acc.a6);
    acc.a7 = fmaf(wt, __uint_as_float(u.w & 0xffff0000u), acc.a7);
}

__global__ __launch_bounds__(128, 5) void msda_sample_v9(
    const ushort* __restrict__ value, const float* __restrict__ comb,
    const float* __restrict__ refp, float* __restrict__ attn_out,
    ushort* __restrict__ out) {
    __shared__ int4   s_idx[4][8][13];   // [q][h][lp], pad 12->13
    __shared__ float4 s_w[4][8][13];
    int tid = threadIdx.x;
    int bq0 = blockIdx.x * 4;

    // ---- phase 1: softmax + tap setup (512 slots, 4 passes of 128) ----
    #pragma unroll
    for (int it = 0; it < 4; it++) {
        int t = tid + it * 128;
        int lp = t & 15;
        int qh = t >> 4;                 // 0..31
        int q = qh >> 3, h = qh & 7;
        int bq = bq0 + q;
        bool active = lp < 12;
        const float* crow = comb + (size_t)bq * 288;
        float logit = active ? crow[192 + h * 12 + lp] : -INFINITY;
        float m = logit;
        m = fmaxf(m, __shfl_xor(m, 1, 16));
        m = fmaxf(m, __shfl_xor(m, 2, 16));
        m = fmaxf(m, __shfl_xor(m, 4, 16));
        m = fmaxf(m, __shfl_xor(m, 8, 16));
        float e = active ? expf(logit - m) : 0.f;
        float s = e;
        s += __shfl_xor(s, 1, 16);
        s += __shfl_xor(s, 2, 16);
        s += __shfl_xor(s, 4, 16);
        s += __shfl_xor(s, 8, 16);
        float aw = e / s;
        if (active) {
            attn_out[(size_t)bq * 96 + h * 12 + lp] = aw;
            int l = lp >> 2;
            int b = bq / SEQ;
            int Wl = 64 >> l;
            float fW = (float)Wl;
            float rx = refp[(size_t)bq * 6 + 2 * l];
            float ry = refp[(size_t)bq * 6 + 2 * l + 1];
            float ox = crow[h * 24 + lp * 2];
            float oy = crow[h * 24 + lp * 2 + 1];
            float x = rx * fW + ox - 0.5f;
            float y = ry * fW + oy - 0.5f;
            float x0f = floorf(x), y0f = floorf(y);
            float wx = x - x0f, wy = y - y0f;
            int x0 = (int)x0f, y0 = (int)y0f;
            int x1 = x0 + 1, y1 = y0 + 1;
            float vx0 = (x0 >= 0 && x0 < Wl) ? 1.f : 0.f;
            float vx1 = (x1 >= 0 && x1 < Wl) ? 1.f : 0.f;
            float vy0 = (y0 >= 0 && y0 < Wl) ? 1.f : 0.f;   // square levels
            float vy1 = (y1 >= 0 && y1 < Wl) ? 1.f : 0.f;
            int xc0 = min(max(x0, 0), Wl - 1);
            int xc1 = min(max(x1, 0), Wl - 1);
            int yc0 = min(max(y0, 0), Wl - 1);
            int yc1 = min(max(y1, 0), Wl - 1);
            int st = (l == 0) ? 0 : ((l == 1) ? 4096 : 5120);
            int rowbase = b * SEQ + st;
            s_idx[q][h][lp] = make_int4((rowbase + yc0 * Wl + xc0) << 8,
                                        (rowbase + yc0 * Wl + xc1) << 8,
                                        (rowbase + yc1 * Wl + xc0) << 8,
                                        (rowbase + yc1 * Wl + xc1) << 8);
            s_w[q][h][lp] = make_float4(aw * (1.f - wx) * (1.f - wy) * vx0 * vy0,
                                        aw * wx * (1.f - wy) * vx1 * vy0,
                                        aw * (1.f - wx) * wy * vx0 * vy1,
                                        aw * wx * wy * vx1 * vy1);
        }
    }
    __syncthreads();

    // ---- phase 2: 2-deep pipelined gather + FMA; 8 ch (16B) per lane ----
    int q = tid >> 5;
    int lane5 = tid & 31;
    int h = lane5 >> 2, d8 = lane5 & 3;
    int bq = bq0 + q;
    int ch0 = h * 32 + d8 * 8;
    const ushort* vb = value + ch0;

    Acc8 acc = {0.f, 0.f, 0.f, 0.f, 0.f, 0.f, 0.f, 0.f};

    int4 iA = s_idx[q][h][0];
    float4 wA = s_w[q][h][0];
    uint4 a0 = *(const uint4*)(vb + iA.x);
    uint4 a1 = *(const uint4*)(vb + iA.y);
    uint4 a2 = *(const uint4*)(vb + iA.z);
    uint4 a3 = *(const uint4*)(vb + iA.w);

    #pragma unroll
    for (int lp = 0; lp < 12; lp++) {
        float4 wB;
        uint4 b0, b1, b2, b3;
        if (lp < 11) {
            int4 iB = s_idx[q][h][lp + 1];
            wB = s_w[q][h][lp + 1];
            b0 = *(const uint4*)(vb + iB.x);
            b1 = *(const uint4*)(vb + iB.y);
            b2 = *(const uint4*)(vb + iB.z);
            b3 = *(const uint4*)(vb + iB.w);
        }
        fma8(acc, wA.x, a0);
        fma8(acc, wA.y, a1);
        fma8(acc, wA.z, a2);
        fma8(acc, wA.w, a3);
        if (lp < 11) {
            wA = wB;
            a0 = b0; a1 = b1; a2 = b2; a3 = b3;
        }
    }

    bf16x8 o;
    o[0] = (short)f2b(acc.a0); o[1] = (short)f2b(acc.a1);
    o[2] = (short)f2b(acc.a2); o[3] = (short)f2b(acc.a3);
    o[4] = (short)f2b(acc.a4); o[5] = (short)f2b(acc.a5);
    o[6] = (short)f2b(acc.a6); o[7] = (short)f2b(acc.a7);
    *(bf16x8*)(out + (size_t)bq * 256 + ch0) = o;
}

// ---------------------------------------------------------------------------
extern "C" void kernel_launch(void* const* d_in, const int* in_sizes, int n_in,
                              void* d_out, int out_size, void* d_ws, size_t ws_size,
                              hipStream_t stream) {
    const float* hidden = (const float*)d_in[0];
    const float* pos    = (const float*)d_in[1];
    const float* refp   = (const float*)d_in[2];
    const float* Wv     = (const float*)d_in[3];
    const float* bv     = (const float*)d_in[4];
    const float* Wo     = (const float*)d_in[5];
    const float* bo     = (const float*)d_in[6];
    const float* Wa     = (const float*)d_in[7];
    const float* ba     = (const float*)d_in[8];
    const float* Wout   = (const float*)d_in[9];
    const float* bout   = (const float*)d_in[10];

    float* out      = (float*)d_out;                       // (B,SEQ,256)
    float* attn_out = out + (size_t)BB * SEQ * DD;         // (B,SEQ,NH,NL,NP)

    const size_t BSD = (size_t)BB * SEQ * DD;              // 5,505,024
    char* w = (char*)d_ws;
    ushort* value_bf = (ushort*)w;  w += BSD * 2;                 // bf16 value
    float*  comb     = (float*)w;   w += (size_t)MTOT * 288 * 4;  // off|logits
    ushort* sampb    = (ushort*)w;  w += BSD * 2;                 // bf16 sampled
    ushort* hb       = (ushort*)w;  w += BSD * 2;                 // bf16 hidden
    ushort* hsb      = (ushort*)w;  w += BSD * 2;                 // bf16 hidden+pos
    ushort* Wt       = (ushort*)w;  w += (size_t)800 * 256 * 2;   // bf16 weights^T
    float*  bcomb    = (float*)w;                                 // 288 bias

    // 1. fused prep: weights transpose + activation bf16 conversion
    {
        int n4 = (int)(BSD / 4);
        prep_all<<<801 + 2048, 256, 0, stream>>>(hidden, pos, Wv, Wo, Wa, Wout,
                                                 bo, ba, (ushort4*)hb, (ushort4*)hsb,
                                                 Wt, bcomb, n4);
    }

    const ushort* Wv_t    = Wt;
    const ushort* Wcomb_t = Wt + (size_t)256 * 256;   // rows: 192 Wo + 96 Wa
    const ushort* Wout_t  = Wt + (size_t)544 * 256;

    // 2. value = hidden @ Wv + bv  -> bf16
    {
        dim3 grid(DD / 128, MTOT / 128);
        gemm_mfma<true><<<grid, 256, 0, stream>>>(hb, Wv_t, bv, value_bf, MTOT, DD, DD);
    }
    // 3. comb = hs @ [Wo|Wa] + [bo|ba]  (N=288, fp32 out)
    {
        dim3 grid(3, MTOT / 128);
        gemm_mfma<false><<<grid, 256, 0, stream>>>(hsb, Wcomb_t, bcomb, comb, MTOT, 288, DD);
    }
    // 4. fused softmax + deformable sampling -> attn_out + sampled bf16
    {
        msda_sample_v9<<<MTOT / 4, 128, 0, stream>>>(value_bf, comb, refp,
                                                     attn_out, sampb);
    }
    // 5. out = sampled @ Wout + bout -> d_out
    {
        dim3 grid(DD / 128, MTOT / 128);
        gemm_mfma<false><<<grid, 256, 0, stream>>>(sampb, Wout_t, bout, out, MTOT, DD, DD);
    }
}

// Round 12
// 136.342 us; speedup vs baseline: 1.9182x; 1.9182x over previous
//
#include <hip/hip_runtime.h>
#include <hip/hip_bf16.h>
#include <math.h>

// Problem constants (Mask2Former pixel decoder / MS-deformable attention)
#define BB 4
#define SEQ 5376
#define DD 256
#define NH 8
#define NL 3
#define NP 4
#define DH 32
#define MTOT (BB * SEQ)          // 21504 rows for all GEMMs

typedef __attribute__((ext_vector_type(8))) short bf16x8;
typedef __attribute__((ext_vector_type(4))) float f32x4;

__device__ __forceinline__ ushort f2b(float f) {
    __hip_bfloat16 h = __float2bfloat16(f);
    return *reinterpret_cast<ushort*>(&h);
}

// ---------------------------------------------------------------------------
// Fused prep: blocks [0,800] transpose weights -> Wt[800][256] bf16 (+bias
// combine at block 800); blocks [801, 801+2048) convert hidden -> bf16 and
// (hidden+pos) -> bf16 (grid-stride).
// ---------------------------------------------------------------------------
__global__ __launch_bounds__(256) void prep_all(
    const float* __restrict__ hidden, const float* __restrict__ pos,
    const float* __restrict__ Wv, const float* __restrict__ Wo,
    const float* __restrict__ Wa, const float* __restrict__ Wout,
    const float* __restrict__ bo, const float* __restrict__ ba,
    ushort4* __restrict__ hb, ushort4* __restrict__ hsb,
    ushort* __restrict__ Wt, float* __restrict__ bcomb, int n4) {
    int bid = blockIdx.x;
    int tid = threadIdx.x;
    if (bid <= 800) {
        if (bid == 800) {
            for (int i = tid; i < 288; i += 256)
                bcomb[i] = (i < 192) ? bo[i] : ba[i - 192];
            return;
        }
        int row = bid;
        const float* src;
        int N, n;
        if (row < 256)      { src = Wv;   N = 256; n = row; }
        else if (row < 448) { src = Wo;   N = 192; n = row - 256; }
        else if (row < 544) { src = Wa;   N = 96;  n = row - 448; }
        else                { src = Wout; N = 256; n = row - 544; }
        float v = src[(size_t)tid * N + n];
        Wt[(size_t)row * 256 + tid] = f2b(v);
        return;
    }
    // activation conversion
    const float4* h4 = (const float4*)hidden;
    const float4* p4 = (const float4*)pos;
    int i = (bid - 801) * 256 + tid;
    int stride = (gridDim.x - 801) * 256;
    for (; i < n4; i += stride) {
        float4 a = h4[i], b = p4[i];
        ushort4 ua, us;
        ua.x = f2b(a.x); ua.y = f2b(a.y); ua.z = f2b(a.z); ua.w = f2b(a.w);
        us.x = f2b(a.x + b.x); us.y = f2b(a.y + b.y);
        us.z = f2b(a.z + b.z); us.w = f2b(a.w + b.w);
        hb[i] = ua;
        hsb[i] = us;
    }
}

// ---------------------------------------------------------------------------
// bf16 MFMA GEMM: C[M,N] = A[M,K]@W[K,N] + bias  (A bf16 [M][K], Wt bf16 [N][K])
// BM=128, BN=128, BK=64. 256 threads = 4 waves 2x2; wave tile 64x64 via 4x4
// fragments of mfma_f32_16x16x32_bf16; 32 MFMA per wave per barrier pair.
// OBF: bf16 output, else fp32. N guarded.
// ---------------------------------------------------------------------------
template<bool OBF>
__global__ __launch_bounds__(256) void gemm_mfma(
    const ushort* __restrict__ A, const ushort* __restrict__ Wt,
    const float* __restrict__ bias, void* __restrict__ Cout,
    int M, int N, int K) {
    const int BM = 128, BN = 128, BK = 64, PK = 72;   // PK: padded LDS row
    __shared__ ushort As[BM][PK];
    __shared__ ushort Bs[BN][PK];
    int bm = blockIdx.y * BM;
    int bn = blockIdx.x * BN;
    int tid = threadIdx.x;
    int lane = tid & 63;
    int wid = tid >> 6;
    int wr = wid >> 1, wc = wid & 1;     // 2x2 wave grid
    int lr = lane & 15;                  // row-in-frag (A) / col (B,C)
    int kg = lane >> 4;                  // k-group 0..3

    f32x4 acc[4][4] = {};

    for (int k0 = 0; k0 < K; k0 += BK) {
        // stage A: 128 rows x 64 bf16 = 1024 chunks of 8 bf16 (16B)
        #pragma unroll
        for (int c = 0; c < 4; c++) {
            int e = tid + 256 * c;
            int row = e >> 3, q = e & 7;
            const ushort* src = A + (size_t)(bm + row) * K + k0 + 8 * q;
            *(bf16x8*)&As[row][8 * q] = *(const bf16x8*)src;
        }
        // stage B: 128 rows x 64 bf16 = 1024 chunks
        #pragma unroll
        for (int c = 0; c < 4; c++) {
            int e = tid + 256 * c;
            int row = e >> 3, q = e & 7;
            int gn = bn + row;
            bf16x8 v = {0, 0, 0, 0, 0, 0, 0, 0};
            if (gn < N) v = *(const bf16x8*)(Wt + (size_t)gn * K + k0 + 8 * q);
            *(bf16x8*)&Bs[row][8 * q] = v;
        }
        __syncthreads();
        #pragma unroll
        for (int ks = 0; ks < 2; ks++) {
            bf16x8 af[4], bfr[4];
            #pragma unroll
            for (int mf = 0; mf < 4; mf++)
                af[mf] = *(bf16x8*)&As[wr * 64 + mf * 16 + lr][ks * 32 + kg * 8];
            #pragma unroll
            for (int nf = 0; nf < 4; nf++)
                bfr[nf] = *(bf16x8*)&Bs[wc * 64 + nf * 16 + lr][ks * 32 + kg * 8];
            #pragma unroll
            for (int mf = 0; mf < 4; mf++)
                #pragma unroll
                for (int nf = 0; nf < 4; nf++)
                    acc[mf][nf] = __builtin_amdgcn_mfma_f32_16x16x32_bf16(
                        af[mf], bfr[nf], acc[mf][nf], 0, 0, 0);
        }
        __syncthreads();
    }

    // epilogue: C[row][col] = acc + bias[col]
    #pragma unroll
    for (int nf = 0; nf < 4; nf++) {
        int gc = bn + wc * 64 + nf * 16 + lr;
        if (gc >= N) continue;
        float bv = bias[gc];
        #pragma unroll
        for (int mf = 0; mf < 4; mf++) {
            int gr0 = bm + wr * 64 + mf * 16 + kg * 4;
            #pragma unroll
            for (int r = 0; r < 4; r++) {
                float v = acc[mf][nf][r] + bv;
                if constexpr (OBF)
                    ((ushort*)Cout)[(size_t)(gr0 + r) * N + gc] = f2b(v);
                else
                    ((float*)Cout)[(size_t)(gr0 + r) * N + gc] = v;
            }
        }
    }
}

// ---------------------------------------------------------------------------
// Deformable sampling v10: fused softmax + tap table + 16B gathers + 2-deep
// tap pipeline. Block = 128 threads (2 waves) = 4 queries (32 lanes/query).
// NO min-wave launch_bounds clamp (R11 lesson: forcing VGPR<pipeline-need
// spills to scratch: 435MB writes, 1% occupancy). Compiler picks VGPR.
// ---------------------------------------------------------------------------
struct Acc8 {
    float a0, a1, a2, a3, a4, a5, a6, a7;
};

__device__ __forceinline__ void fma8(Acc8& acc, float wt, uint4 u) {
    acc.a0 = fmaf(wt, __uint_as_float(u.x << 16), acc.a0);
    acc.a1 = fmaf(wt, __uint_as_float(u.x & 0xffff0000u), acc.a1);
    acc.a2 = fmaf(wt, __uint_as_float(u.y << 16), acc.a2);
    acc.a3 = fmaf(wt, __uint_as_float(u.y & 0xffff0000u), acc.a3);
    acc.a4 = fmaf(wt, __uint_as_float(u.z << 16), acc.a4);
    acc.a5 = fmaf(wt, __uint_as_float(u.z & 0xffff0000u), acc.a5);
    acc.a6 = fmaf(wt, __uint_as_float(u.w << 16), acc.a6);
    acc.a7 = fmaf(wt, __uint_as_float(u.w & 0xffff0000u), acc.a7);
}

__global__ __launch_bounds__(128) void msda_sample_v10(
    const ushort* __restrict__ value, const float* __restrict__ comb,
    const float* __restrict__ refp, float* __restrict__ attn_out,
    ushort* __restrict__ out) {
    __shared__ int4   s_idx[4][8][13];   // [q][h][lp], pad 12->13
    __shared__ float4 s_w[4][8][13];
    int tid = threadIdx.x;
    int bq0 = blockIdx.x * 4;

    // ---- phase 1: softmax + tap setup (512 slots, 4 passes of 128) ----
    #pragma unroll
    for (int it = 0; it < 4; it++) {
        int t = tid + it * 128;
        int lp = t & 15;
        int qh = t >> 4;                 // 0..31
        int q = qh >> 3, h = qh & 7;
        int bq = bq0 + q;
        bool active = lp < 12;
        const float* crow = comb + (size_t)bq * 288;
        float logit = active ? crow[192 + h * 12 + lp] : -INFINITY;
        float m = logit;
        m = fmaxf(m, __shfl_xor(m, 1, 16));
        m = fmaxf(m, __shfl_xor(m, 2, 16));
        m = fmaxf(m, __shfl_xor(m, 4, 16));
        m = fmaxf(m, __shfl_xor(m, 8, 16));
        float e = active ? expf(logit - m) : 0.f;
        float s = e;
        s += __shfl_xor(s, 1, 16);
        s += __shfl_xor(s, 2, 16);
        s += __shfl_xor(s, 4, 16);
        s += __shfl_xor(s, 8, 16);
        float aw = e / s;
        if (active) {
            attn_out[(size_t)bq * 96 + h * 12 + lp] = aw;
            int l = lp >> 2;
            int b = bq / SEQ;
            int Wl = 64 >> l;
            float fW = (float)Wl;
            float rx = refp[(size_t)bq * 6 + 2 * l];
            float ry = refp[(size_t)bq * 6 + 2 * l + 1];
            float ox = crow[h * 24 + lp * 2];
            float oy = crow[h * 24 + lp * 2 + 1];
            float x = rx * fW + ox - 0.5f;
            float y = ry * fW + oy - 0.5f;
            float x0f = floorf(x), y0f = floorf(y);
            float wx = x - x0f, wy = y - y0f;
            int x0 = (int)x0f, y0 = (int)y0f;
            int x1 = x0 + 1, y1 = y0 + 1;
            float vx0 = (x0 >= 0 && x0 < Wl) ? 1.f : 0.f;
            float vx1 = (x1 >= 0 && x1 < Wl) ? 1.f : 0.f;
            float vy0 = (y0 >= 0 && y0 < Wl) ? 1.f : 0.f;   // square levels
            float vy1 = (y1 >= 0 && y1 < Wl) ? 1.f : 0.f;
            int xc0 = min(max(x0, 0), Wl - 1);
            int xc1 = min(max(x1, 0), Wl - 1);
            int yc0 = min(max(y0, 0), Wl - 1);
            int yc1 = min(max(y1, 0), Wl - 1);
            int st = (l == 0) ? 0 : ((l == 1) ? 4096 : 5120);
            int rowbase = b * SEQ + st;
            s_idx[q][h][lp] = make_int4((rowbase + yc0 * Wl + xc0) << 8,
                                        (rowbase + yc0 * Wl + xc1) << 8,
                                        (rowbase + yc1 * Wl + xc0) << 8,
                                        (rowbase + yc1 * Wl + xc1) << 8);
            s_w[q][h][lp] = make_float4(aw * (1.f - wx) * (1.f - wy) * vx0 * vy0,
                                        aw * wx * (1.f - wy) * vx1 * vy0,
                                        aw * (1.f - wx) * wy * vx0 * vy1,
                                        aw * wx * wy * vx1 * vy1);
        }
    }
    __syncthreads();

    // ---- phase 2: 2-deep pipelined gather + FMA; 8 ch (16B) per lane ----
    int q = tid >> 5;
    int lane5 = tid & 31;
    int h = lane5 >> 2, d8 = lane5 & 3;
    int bq = bq0 + q;
    int ch0 = h * 32 + d8 * 8;
    const ushort* vb = value + ch0;

    Acc8 acc = {0.f, 0.f, 0.f, 0.f, 0.f, 0.f, 0.f, 0.f};

    int4 iA = s_idx[q][h][0];
    float4 wA = s_w[q][h][0];
    uint4 a0 = *(const uint4*)(vb + iA.x);
    uint4 a1 = *(const uint4*)(vb + iA.y);
    uint4 a2 = *(const uint4*)(vb + iA.z);
    uint4 a3 = *(const uint4*)(vb + iA.w);

    #pragma unroll
    for (int lp = 0; lp < 12; lp++) {
        float4 wB;
        uint4 b0, b1, b2, b3;
        if (lp < 11) {
            int4 iB = s_idx[q][h][lp + 1];
            wB = s_w[q][h][lp + 1];
            b0 = *(const uint4*)(vb + iB.x);
            b1 = *(const uint4*)(vb + iB.y);
            b2 = *(const uint4*)(vb + iB.z);
            b3 = *(const uint4*)(vb + iB.w);
        }
        fma8(acc, wA.x, a0);
        fma8(acc, wA.y, a1);
        fma8(acc, wA.z, a2);
        fma8(acc, wA.w, a3);
        if (lp < 11) {
            wA = wB;
            a0 = b0; a1 = b1; a2 = b2; a3 = b3;
        }
    }

    bf16x8 o;
    o[0] = (short)f2b(acc.a0); o[1] = (short)f2b(acc.a1);
    o[2] = (short)f2b(acc.a2); o[3] = (short)f2b(acc.a3);
    o[4] = (short)f2b(acc.a4); o[5] = (short)f2b(acc.a5);
    o[6] = (short)f2b(acc.a6); o[7] = (short)f2b(acc.a7);
    *(bf16x8*)(out + (size_t)bq * 256 + ch0) = o;
}

// ---------------------------------------------------------------------------
extern "C" void kernel_launch(void* const* d_in, const int* in_sizes, int n_in,
                              void* d_out, int out_size, void* d_ws, size_t ws_size,
                              hipStream_t stream) {
    const float* hidden = (const float*)d_in[0];
    const float* pos    = (const float*)d_in[1];
    const float* refp   = (const float*)d_in[2];
    const float* Wv     = (const float*)d_in[3];
    const float* bv     = (const float*)d_in[4];
    const float* Wo     = (const float*)d_in[5];
    const float* bo     = (const float*)d_in[6];
    const float* Wa     = (const float*)d_in[7];
    const float* ba     = (const float*)d_in[8];
    const float* Wout   = (const float*)d_in[9];
    const float* bout   = (const float*)d_in[10];

    float* out      = (float*)d_out;                       // (B,SEQ,256)
    float* attn_out = out + (size_t)BB * SEQ * DD;         // (B,SEQ,NH,NL,NP)

    const size_t BSD = (size_t)BB * SEQ * DD;              // 5,505,024
    char* w = (char*)d_ws;
    ushort* value_bf = (ushort*)w;  w += BSD * 2;                 // bf16 value
    float*  comb     = (float*)w;   w += (size_t)MTOT * 288 * 4;  // off|logits
    ushort* sampb    = (ushort*)w;  w += BSD * 2;                 // bf16 sampled
    ushort* hb       = (ushort*)w;  w += BSD * 2;                 // bf16 hidden
    ushort* hsb      = (ushort*)w;  w += BSD * 2;                 // bf16 hidden+pos
    ushort* Wt       = (ushort*)w;  w += (size_t)800 * 256 * 2;   // bf16 weights^T
    float*  bcomb    = (float*)w;                                 // 288 bias

    // 1. fused prep: weights transpose + activation bf16 conversion
    {
        int n4 = (int)(BSD / 4);
        prep_all<<<801 + 2048, 256, 0, stream>>>(hidden, pos, Wv, Wo, Wa, Wout,
                                                 bo, ba, (ushort4*)hb, (ushort4*)hsb,
                                                 Wt, bcomb, n4);
    }

    const ushort* Wv_t    = Wt;
    const ushort* Wcomb_t = Wt + (size_t)256 * 256;   // rows: 192 Wo + 96 Wa
    const ushort* Wout_t  = Wt + (size_t)544 * 256;

    // 2. value = hidden @ Wv + bv  -> bf16
    {
        dim3 grid(DD / 128, MTOT / 128);
        gemm_mfma<true><<<grid, 256, 0, stream>>>(hb, Wv_t, bv, value_bf, MTOT, DD, DD);
    }
    // 3. comb = hs @ [Wo|Wa] + [bo|ba]  (N=288, fp32 out)
    {
        dim3 grid(3, MTOT / 128);
        gemm_mfma<false><<<grid, 256, 0, stream>>>(hsb, Wcomb_t, bcomb, comb, MTOT, 288, DD);
    }
    // 4. fused softmax + deformable sampling -> attn_out + sampled bf16
    {
        msda_sample_v10<<<MTOT / 4, 128, 0, stream>>>(value_bf, comb, refp,
                                                      attn_out, sampb);
    }
    // 5. out = sampled @ Wout + bout -> d_out
    {
        dim3 grid(DD / 128, MTOT / 128);
        gemm_mfma<false><<<grid, 256, 0, stream>>>(sampb, Wout_t, bout, out, MTOT, DD, DD);
    }
}

// Round 13
// 83.427 us; speedup vs baseline: 3.1349x; 1.6343x over previous
//
#include <hip/hip_runtime.h>
#include <hip/hip_bf16.h>
#include <math.h>

// Problem constants (Mask2Former pixel decoder / MS-deformable attention)
#define BB 4
#define SEQ 5376
#define DD 256
#define NH 8
#define NL 3
#define NP 4
#define DH 32
#define MTOT (BB * SEQ)          // 21504 rows for all GEMMs

typedef __attribute__((ext_vector_type(8))) short bf16x8;
typedef __attribute__((ext_vector_type(4))) float f32x4;

#define GLD_LDS16(src, dst) __builtin_amdgcn_global_load_lds( \
    (const __attribute__((address_space(1))) void*)(src),     \
    (__attribute__((address_space(3))) void*)(dst), 16, 0, 0)

__device__ __forceinline__ ushort f2b(float f) {
    __hip_bfloat16 h = __float2bfloat16(f);
    return *reinterpret_cast<ushort*>(&h);
}

// ---------------------------------------------------------------------------
// Fused prep: blocks [0,800] transpose weights -> Wt[800][256] bf16 (+bias
// combine at block 800); blocks [801, 801+2048) convert hidden -> bf16 and
// (hidden+pos) -> bf16 (grid-stride).
// ---------------------------------------------------------------------------
__global__ __launch_bounds__(256) void prep_all(
    const float* __restrict__ hidden, const float* __restrict__ pos,
    const float* __restrict__ Wv, const float* __restrict__ Wo,
    const float* __restrict__ Wa, const float* __restrict__ Wout,
    const float* __restrict__ bo, const float* __restrict__ ba,
    ushort4* __restrict__ hb, ushort4* __restrict__ hsb,
    ushort* __restrict__ Wt, float* __restrict__ bcomb, int n4) {
    int bid = blockIdx.x;
    int tid = threadIdx.x;
    if (bid <= 800) {
        if (bid == 800) {
            for (int i = tid; i < 288; i += 256)
                bcomb[i] = (i < 192) ? bo[i] : ba[i - 192];
            return;
        }
        int row = bid;
        const float* src;
        int N, n;
        if (row < 256)      { src = Wv;   N = 256; n = row; }
        else if (row < 448) { src = Wo;   N = 192; n = row - 256; }
        else if (row < 544) { src = Wa;   N = 96;  n = row - 448; }
        else                { src = Wout; N = 256; n = row - 544; }
        float v = src[(size_t)tid * N + n];
        Wt[(size_t)row * 256 + tid] = f2b(v);
        return;
    }
    // activation conversion
    const float4* h4 = (const float4*)hidden;
    const float4* p4 = (const float4*)pos;
    int i = (bid - 801) * 256 + tid;
    int stride = (gridDim.x - 801) * 256;
    for (; i < n4; i += stride) {
        float4 a = h4[i], b = p4[i];
        ushort4 ua, us;
        ua.x = f2b(a.x); ua.y = f2b(a.y); ua.z = f2b(a.z); ua.w = f2b(a.w);
        us.x = f2b(a.x + b.x); us.y = f2b(a.y + b.y);
        us.z = f2b(a.z + b.z); us.w = f2b(a.w + b.w);
        hb[i] = ua;
        hsb[i] = us;
    }
}

// ---------------------------------------------------------------------------
// bf16 MFMA GEMM with global_load_lds staging + chunk-XOR swizzled LDS.
// BM=128, BN=128, BK=64. LDS tiles are LINEAR [128][64] ushort (128B rows);
// 16B chunk c of row r holds global chunk c^(r&7) (pre-swizzled global src,
// rule 21: swizzle both sides). Fragment ds_reads apply the same XOR ->
// 8 distinct chunk slots across lr=0..7 -> conflict-free (2-way alias free).
// 256 threads = 4 waves 2x2; wave tile 64x64; 32 MFMA/wave per barrier pair.
// OBF: bf16 output, else fp32. N guarded on store; B-tile OOB rows read
// neighboring Wt rows (finite, in-buffer, discarded by store guard).
// ---------------------------------------------------------------------------
template<bool OBF>
__global__ __launch_bounds__(256) void gemm_mfma(
    const ushort* __restrict__ A, const ushort* __restrict__ Wt,
    const float* __restrict__ bias, void* __restrict__ Cout,
    int M, int N, int K) {
    const int BK = 64;
    __shared__ ushort As[128 * 64];
    __shared__ ushort Bs[128 * 64];
    int bm = blockIdx.y * 128;
    int bn = blockIdx.x * 128;
    int tid = threadIdx.x;
    int lane = tid & 63;
    int wid = tid >> 6;
    int wr = wid >> 1, wc = wid & 1;     // 2x2 wave grid
    int lr = lane & 15;                  // row-in-frag (A) / col (B,C)
    int kg = lane >> 4;                  // k-group 0..3

    f32x4 acc[4][4] = {};

    for (int k0 = 0; k0 < K; k0 += BK) {
        // stage A+B: 1024 16B chunks each, direct global->LDS, swizzled src
        #pragma unroll
        for (int c = 0; c < 4; c++) {
            int e = tid + 256 * c;           // chunk id 0..1023
            int row = e >> 3;                // tile row 0..127
            int ch = e & 7;                  // lds chunk in row
            int gch = ch ^ (row & 7);        // swizzled global chunk
            GLD_LDS16(A + (size_t)(bm + row) * K + k0 + 8 * gch, &As[e * 8]);
            GLD_LDS16(Wt + (size_t)(bn + row) * K + k0 + 8 * gch, &Bs[e * 8]);
        }
        __syncthreads();
        #pragma unroll
        for (int ks = 0; ks < 2; ks++) {
            bf16x8 af[4], bfr[4];
            #pragma unroll
            for (int mf = 0; mf < 4; mf++) {
                int R = wr * 64 + mf * 16 + lr;
                int sc = (ks * 4 + kg) ^ (R & 7);
                af[mf] = *(bf16x8*)&As[R * 64 + sc * 8];
            }
            #pragma unroll
            for (int nf = 0; nf < 4; nf++) {
                int R = wc * 64 + nf * 16 + lr;
                int sc = (ks * 4 + kg) ^ (R & 7);
                bfr[nf] = *(bf16x8*)&Bs[R * 64 + sc * 8];
            }
            #pragma unroll
            for (int mf = 0; mf < 4; mf++)
                #pragma unroll
                for (int nf = 0; nf < 4; nf++)
                    acc[mf][nf] = __builtin_amdgcn_mfma_f32_16x16x32_bf16(
                        af[mf], bfr[nf], acc[mf][nf], 0, 0, 0);
        }
        __syncthreads();
    }

    // epilogue: C[row][col] = acc + bias[col]
    #pragma unroll
    for (int nf = 0; nf < 4; nf++) {
        int gc = bn + wc * 64 + nf * 16 + lr;
        if (gc >= N) continue;
        float bv = bias[gc];
        #pragma unroll
        for (int mf = 0; mf < 4; mf++) {
            int gr0 = bm + wr * 64 + mf * 16 + kg * 4;
            #pragma unroll
            for (int r = 0; r < 4; r++) {
                float v = acc[mf][nf][r] + bv;
                if constexpr (OBF)
                    ((ushort*)Cout)[(size_t)(gr0 + r) * N + gc] = f2b(v);
                else
                    ((float*)Cout)[(size_t)(gr0 + r) * N + gc] = v;
            }
        }
    }
}

// ---------------------------------------------------------------------------
// Deformable sampling v7 (R9 best): fused softmax + tap table + 16B gathers,
// no manual pipelining. Block = 128 threads (2 waves) = 4 queries.
// ---------------------------------------------------------------------------
struct Acc8 {
    float a0, a1, a2, a3, a4, a5, a6, a7;
};

__device__ __forceinline__ void fma8(Acc8& acc, float wt, uint4 u) {
    acc.a0 = fmaf(wt, __uint_as_float(u.x << 16), acc.a0);
    acc.a1 = fmaf(wt, __uint_as_float(u.x & 0xffff0000u), acc.a1);
    acc.a2 = fmaf(wt, __uint_as_float(u.y << 16), acc.a2);
    acc.a3 = fmaf(wt, __uint_as_float(u.y & 0xffff0000u), acc.a3);
    acc.a4 = fmaf(wt, __uint_as_float(u.z << 16), acc.a4);
    acc.a5 = fmaf(wt, __uint_as_float(u.z & 0xffff0000u), acc.a5);
    acc.a6 = fmaf(wt, __uint_as_float(u.w << 16), acc.a6);
    acc.a7 = fmaf(wt, __uint_as_float(u.w & 0xffff0000u), acc.a7);
}

__global__ __launch_bounds__(128) void msda_sample_v7(
    const ushort* __restrict__ value, const float* __restrict__ comb,
    const float* __restrict__ refp, float* __restrict__ attn_out,
    ushort* __restrict__ out) {
    __shared__ int4   s_idx[4][8][13];   // [q][h][lp], pad 12->13
    __shared__ float4 s_w[4][8][13];
    int tid = threadIdx.x;
    int bq0 = blockIdx.x * 4;

    // ---- phase 1: softmax + tap setup (512 slots, 4 passes of 128) ----
    #pragma unroll
    for (int it = 0; it < 4; it++) {
        int t = tid + it * 128;
        int lp = t & 15;
        int qh = t >> 4;                 // 0..31
        int q = qh >> 3, h = qh & 7;
        int bq = bq0 + q;
        bool active = lp < 12;
        const float* crow = comb + (size_t)bq * 288;
        float logit = active ? crow[192 + h * 12 + lp] : -INFINITY;
        float m = logit;
        m = fmaxf(m, __shfl_xor(m, 1, 16));
        m = fmaxf(m, __shfl_xor(m, 2, 16));
        m = fmaxf(m, __shfl_xor(m, 4, 16));
        m = fmaxf(m, __shfl_xor(m, 8, 16));
        float e = active ? expf(logit - m) : 0.f;
        float s = e;
        s += __shfl_xor(s, 1, 16);
        s += __shfl_xor(s, 2, 16);
        s += __shfl_xor(s, 4, 16);
        s += __shfl_xor(s, 8, 16);
        float aw = e / s;
        if (active) {
            attn_out[(size_t)bq * 96 + h * 12 + lp] = aw;
            int l = lp >> 2;
            int b = bq / SEQ;
            int Wl = 64 >> l;
            float fW = (float)Wl;
            float rx = refp[(size_t)bq * 6 + 2 * l];
            float ry = refp[(size_t)bq * 6 + 2 * l + 1];
            float ox = crow[h * 24 + lp * 2];
            float oy = crow[h * 24 + lp * 2 + 1];
            float x = rx * fW + ox - 0.5f;
            float y = ry * fW + oy - 0.5f;
            float x0f = floorf(x), y0f = floorf(y);
            float wx = x - x0f, wy = y - y0f;
            int x0 = (int)x0f, y0 = (int)y0f;
            int x1 = x0 + 1, y1 = y0 + 1;
            float vx0 = (x0 >= 0 && x0 < Wl) ? 1.f : 0.f;
            float vx1 = (x1 >= 0 && x1 < Wl) ? 1.f : 0.f;
            float vy0 = (y0 >= 0 && y0 < Wl) ? 1.f : 0.f;   // square levels
            float vy1 = (y1 >= 0 && y1 < Wl) ? 1.f : 0.f;
            int xc0 = min(max(x0, 0), Wl - 1);
            int xc1 = min(max(x1, 0), Wl - 1);
            int yc0 = min(max(y0, 0), Wl - 1);
            int yc1 = min(max(y1, 0), Wl - 1);
            int st = (l == 0) ? 0 : ((l == 1) ? 4096 : 5120);
            int rowbase = b * SEQ + st;
            s_idx[q][h][lp] = make_int4((rowbase + yc0 * Wl + xc0) << 8,
                                        (rowbase + yc0 * Wl + xc1) << 8,
                                        (rowbase + yc1 * Wl + xc0) << 8,
                                        (rowbase + yc1 * Wl + xc1) << 8);
            s_w[q][h][lp] = make_float4(aw * (1.f - wx) * (1.f - wy) * vx0 * vy0,
                                        aw * wx * (1.f - wy) * vx1 * vy0,
                                        aw * (1.f - wx) * wy * vx0 * vy1,
                                        aw * wx * wy * vx1 * vy1);
        }
    }
    __syncthreads();

    // ---- phase 2: gather + FMA; 8 channels (16B) per lane ----
    int wave = tid >> 6, lane = tid & 63;
    int q2 = lane >> 5;
    int lane5 = lane & 31;
    int h = lane5 >> 2, d8 = lane5 & 3;
    int q = wave * 2 + q2;
    int bq = bq0 + q;
    int ch0 = h * 32 + d8 * 8;
    const ushort* vb = value + ch0;

    Acc8 acc = {0.f, 0.f, 0.f, 0.f, 0.f, 0.f, 0.f, 0.f};
    #pragma unroll
    for (int lp = 0; lp < 12; lp++) {
        int4 ii = s_idx[q][h][lp];
        float4 ww = s_w[q][h][lp];
        uint4 u0 = *(const uint4*)(vb + ii.x);
        uint4 u1 = *(const uint4*)(vb + ii.y);
        uint4 u2 = *(const uint4*)(vb + ii.z);
        uint4 u3 = *(const uint4*)(vb + ii.w);
        fma8(acc, ww.x, u0);
        fma8(acc, ww.y, u1);
        fma8(acc, ww.z, u2);
        fma8(acc, ww.w, u3);
    }

    bf16x8 o;
    o[0] = (short)f2b(acc.a0); o[1] = (short)f2b(acc.a1);
    o[2] = (short)f2b(acc.a2); o[3] = (short)f2b(acc.a3);
    o[4] = (short)f2b(acc.a4); o[5] = (short)f2b(acc.a5);
    o[6] = (short)f2b(acc.a6); o[7] = (short)f2b(acc.a7);
    *(bf16x8*)(out + (size_t)bq * 256 + ch0) = o;
}

// ---------------------------------------------------------------------------
extern "C" void kernel_launch(void* const* d_in, const int* in_sizes, int n_in,
                              void* d_out, int out_size, void* d_ws, size_t ws_size,
                              hipStream_t stream) {
    const float* hidden = (const float*)d_in[0];
    const float* pos    = (const float*)d_in[1];
    const float* refp   = (const float*)d_in[2];
    const float* Wv     = (const float*)d_in[3];
    const float* bv     = (const float*)d_in[4];
    const float* Wo     = (const float*)d_in[5];
    const float* bo     = (const float*)d_in[6];
    const float* Wa     = (const float*)d_in[7];
    const float* ba     = (const float*)d_in[8];
    const float* Wout   = (const float*)d_in[9];
    const float* bout   = (const float*)d_in[10];

    float* out      = (float*)d_out;                       // (B,SEQ,256)
    float* attn_out = out + (size_t)BB * SEQ * DD;         // (B,SEQ,NH,NL,NP)

    const size_t BSD = (size_t)BB * SEQ * DD;              // 5,505,024
    char* w = (char*)d_ws;
    ushort* value_bf = (ushort*)w;  w += BSD * 2;                 // bf16 value
    float*  comb     = (float*)w;   w += (size_t)MTOT * 288 * 4;  // off|logits
    ushort* sampb    = (ushort*)w;  w += BSD * 2;                 // bf16 sampled
    ushort* hb       = (ushort*)w;  w += BSD * 2;                 // bf16 hidden
    ushort* hsb      = (ushort*)w;  w += BSD * 2;                 // bf16 hidden+pos
    ushort* Wt       = (ushort*)w;  w += (size_t)800 * 256 * 2;   // bf16 weights^T
    float*  bcomb    = (float*)w;                                 // 288 bias

    // 1. fused prep: weights transpose + activation bf16 conversion
    {
        int n4 = (int)(BSD / 4);
        prep_all<<<801 + 2048, 256, 0, stream>>>(hidden, pos, Wv, Wo, Wa, Wout,
                                                 bo, ba, (ushort4*)hb, (ushort4*)hsb,
                                                 Wt, bcomb, n4);
    }

    const ushort* Wv_t    = Wt;
    const ushort* Wcomb_t = Wt + (size_t)256 * 256;   // rows: 192 Wo + 96 Wa
    const ushort* Wout_t  = Wt + (size_t)544 * 256;

    // 2. value = hidden @ Wv + bv  -> bf16
    {
        dim3 grid(DD / 128, MTOT / 128);
        gemm_mfma<true><<<grid, 256, 0, stream>>>(hb, Wv_t, bv, value_bf, MTOT, DD, DD);
    }
    // 3. comb = hs @ [Wo|Wa] + [bo|ba]  (N=288, fp32 out)
    {
        dim3 grid(3, MTOT / 128);
        gemm_mfma<false><<<grid, 256, 0, stream>>>(hsb, Wcomb_t, bcomb, comb, MTOT, 288, DD);
    }
    // 4. fused softmax + deformable sampling -> attn_out + sampled bf16
    {
        msda_sample_v7<<<MTOT / 4, 128, 0, stream>>>(value_bf, comb, refp,
                                                     attn_out, sampb);
    }
    // 5. out = sampled @ Wout + bout -> d_out
    {
        dim3 grid(DD / 128, MTOT / 128);
        gemm_mfma<false><<<grid, 256, 0, stream>>>(sampb, Wout_t, bout, out, MTOT, DD, DD);
    }
}

// Round 14
// 82.404 us; speedup vs baseline: 3.1738x; 1.0124x over previous
//
#include <hip/hip_runtime.h>
#include <hip/hip_bf16.h>
#include <math.h>

// Problem constants (Mask2Former pixel decoder / MS-deformable attention)
#define BB 4
#define SEQ 5376
#define DD 256
#define NH 8
#define NL 3
#define NP 4
#define DH 32
#define MTOT (BB * SEQ)          // 21504 rows for all GEMMs

typedef __attribute__((ext_vector_type(8))) short bf16x8;
typedef __attribute__((ext_vector_type(4))) float f32x4;

#define GLD_LDS16(src, dst) __builtin_amdgcn_global_load_lds( \
    (const __attribute__((address_space(1))) void*)(src),     \
    (__attribute__((address_space(3))) void*)(dst), 16, 0, 0)

__device__ __forceinline__ ushort f2b(float f) {
    __hip_bfloat16 h = __float2bfloat16(f);
    return *reinterpret_cast<ushort*>(&h);
}

// ---------------------------------------------------------------------------
// Fused prep: blocks [0,800] transpose weights -> Wt[800][256] bf16 (+bias
// combine at block 800); blocks [801, 801+2048) convert hidden -> bf16 and
// (hidden+pos) -> bf16 (grid-stride).
// ---------------------------------------------------------------------------
__global__ __launch_bounds__(256) void prep_all(
    const float* __restrict__ hidden, const float* __restrict__ pos,
    const float* __restrict__ Wv, const float* __restrict__ Wo,
    const float* __restrict__ Wa, const float* __restrict__ Wout,
    const float* __restrict__ bo, const float* __restrict__ ba,
    ushort4* __restrict__ hb, ushort4* __restrict__ hsb,
    ushort* __restrict__ Wt, float* __restrict__ bcomb, int n4) {
    int bid = blockIdx.x;
    int tid = threadIdx.x;
    if (bid <= 800) {
        if (bid == 800) {
            for (int i = tid; i < 288; i += 256)
                bcomb[i] = (i < 192) ? bo[i] : ba[i - 192];
            return;
        }
        int row = bid;
        const float* src;
        int N, n;
        if (row < 256)      { src = Wv;   N = 256; n = row; }
        else if (row < 448) { src = Wo;   N = 192; n = row - 256; }
        else if (row < 544) { src = Wa;   N = 96;  n = row - 448; }
        else                { src = Wout; N = 256; n = row - 544; }
        float v = src[(size_t)tid * N + n];
        Wt[(size_t)row * 256 + tid] = f2b(v);
        return;
    }
    // activation conversion
    const float4* h4 = (const float4*)hidden;
    const float4* p4 = (const float4*)pos;
    int i = (bid - 801) * 256 + tid;
    int stride = (gridDim.x - 801) * 256;
    for (; i < n4; i += stride) {
        float4 a = h4[i], b = p4[i];
        ushort4 ua, us;
        ua.x = f2b(a.x); ua.y = f2b(a.y); ua.z = f2b(a.z); ua.w = f2b(a.w);
        us.x = f2b(a.x + b.x); us.y = f2b(a.y + b.y);
        us.z = f2b(a.z + b.z); us.w = f2b(a.w + b.w);
        hb[i] = ua;
        hsb[i] = us;
    }
}

// ---------------------------------------------------------------------------
// Dual bf16 MFMA GEMM (one dispatch = value GEMM + comb GEMM for grid fill).
// Blocks [0,336): value = hb @ Wv^T + bv -> bf16, N=256 (2 col-blocks x 168).
// Blocks [336,840): comb = hsb @ Wcomb^T + bcomb -> fp32, N=288 (3 x 168).
// BM=128, BN=128, BK=64; global_load_lds staging, chunk-XOR swizzle both
// sides (R13-proven). 256 thr = 4 waves 2x2; 32 MFMA/wave per barrier pair.
// ---------------------------------------------------------------------------
__global__ __launch_bounds__(256) void gemm_dual(
    const ushort* __restrict__ hb, const ushort* __restrict__ hsb,
    const ushort* __restrict__ Wv_t, const ushort* __restrict__ Wcomb_t,
    const float* __restrict__ bv, const float* __restrict__ bcomb,
    ushort* __restrict__ value_bf, float* __restrict__ comb) {
    const int K = 256, BK = 64;
    __shared__ ushort As[128 * 64];
    __shared__ ushort Bs[128 * 64];

    int b = blockIdx.x;
    const ushort* A;
    const ushort* W;
    const float* bias;
    int bn, bm, N;
    bool obf;
    if (b < 336) {
        A = hb;  W = Wv_t;    bias = bv;    N = 256; obf = true;
        bn = (b & 1) * 128;   bm = (b >> 1) * 128;
    } else {
        int bb = b - 336;
        A = hsb; W = Wcomb_t; bias = bcomb; N = 288; obf = false;
        bn = (bb % 3) * 128;  bm = (bb / 3) * 128;
    }

    int tid = threadIdx.x;
    int lane = tid & 63;
    int wid = tid >> 6;
    int wr = wid >> 1, wc = wid & 1;
    int lr = lane & 15;
    int kg = lane >> 4;

    f32x4 acc[4][4] = {};

    for (int k0 = 0; k0 < K; k0 += BK) {
        #pragma unroll
        for (int c = 0; c < 4; c++) {
            int e = tid + 256 * c;           // chunk id 0..1023
            int row = e >> 3;
            int ch = e & 7;
            int gch = ch ^ (row & 7);
            GLD_LDS16(A + (size_t)(bm + row) * K + k0 + 8 * gch, &As[e * 8]);
            GLD_LDS16(W + (size_t)(bn + row) * K + k0 + 8 * gch, &Bs[e * 8]);
        }
        __syncthreads();
        #pragma unroll
        for (int ks = 0; ks < 2; ks++) {
            bf16x8 af[4], bfr[4];
            #pragma unroll
            for (int mf = 0; mf < 4; mf++) {
                int R = wr * 64 + mf * 16 + lr;
                int sc = (ks * 4 + kg) ^ (R & 7);
                af[mf] = *(bf16x8*)&As[R * 64 + sc * 8];
            }
            #pragma unroll
            for (int nf = 0; nf < 4; nf++) {
                int R = wc * 64 + nf * 16 + lr;
                int sc = (ks * 4 + kg) ^ (R & 7);
                bfr[nf] = *(bf16x8*)&Bs[R * 64 + sc * 8];
            }
            #pragma unroll
            for (int mf = 0; mf < 4; mf++)
                #pragma unroll
                for (int nf = 0; nf < 4; nf++)
                    acc[mf][nf] = __builtin_amdgcn_mfma_f32_16x16x32_bf16(
                        af[mf], bfr[nf], acc[mf][nf], 0, 0, 0);
        }
        __syncthreads();
    }

    #pragma unroll
    for (int nf = 0; nf < 4; nf++) {
        int gc = bn + wc * 64 + nf * 16 + lr;
        if (gc >= N) continue;
        float bvv = bias[gc];
        #pragma unroll
        for (int mf = 0; mf < 4; mf++) {
            int gr0 = bm + wr * 64 + mf * 16 + kg * 4;
            #pragma unroll
            for (int r = 0; r < 4; r++) {
                float v = acc[mf][nf][r] + bvv;
                if (obf)
                    value_bf[(size_t)(gr0 + r) * 256 + gc] = f2b(v);
                else
                    comb[(size_t)(gr0 + r) * 288 + gc] = v;
            }
        }
    }
}

// ---------------------------------------------------------------------------
// Output GEMM: out = sampb @ Wout^T + bout, N=256, fp32 out.
// BM=128, BN=64 (672 blocks for grid fill), BK=64; gld_lds + XOR swizzle.
// 4 waves 2x2; wave tile 64x32; 16 MFMA/wave per barrier pair.
// ---------------------------------------------------------------------------
__global__ __launch_bounds__(256) void gemm_out(
    const ushort* __restrict__ A, const ushort* __restrict__ Wt,
    const float* __restrict__ bias, float* __restrict__ C) {
    const int K = 256, BK = 64;
    __shared__ ushort As[128 * 64];
    __shared__ ushort Bs[64 * 64];
    int bm = blockIdx.y * 128;
    int bn = blockIdx.x * 64;
    int tid = threadIdx.x;
    int lane = tid & 63;
    int wid = tid >> 6;
    int wr = wid >> 1, wc = wid & 1;
    int lr = lane & 15;
    int kg = lane >> 4;

    f32x4 acc[4][2] = {};

    for (int k0 = 0; k0 < K; k0 += BK) {
        #pragma unroll
        for (int c = 0; c < 4; c++) {
            int e = tid + 256 * c;
            int row = e >> 3;
            int ch = e & 7;
            int gch = ch ^ (row & 7);
            GLD_LDS16(A + (size_t)(bm + row) * K + k0 + 8 * gch, &As[e * 8]);
        }
        #pragma unroll
        for (int c = 0; c < 2; c++) {
            int e = tid + 256 * c;           // 0..511
            int row = e >> 3;                // 0..63
            int ch = e & 7;
            int gch = ch ^ (row & 7);
            GLD_LDS16(Wt + (size_t)(bn + row) * K + k0 + 8 * gch, &Bs[e * 8]);
        }
        __syncthreads();
        #pragma unroll
        for (int ks = 0; ks < 2; ks++) {
            bf16x8 af[4], bfr[2];
            #pragma unroll
            for (int mf = 0; mf < 4; mf++) {
                int R = wr * 64 + mf * 16 + lr;
                int sc = (ks * 4 + kg) ^ (R & 7);
                af[mf] = *(bf16x8*)&As[R * 64 + sc * 8];
            }
            #pragma unroll
            for (int nf = 0; nf < 2; nf++) {
                int R = wc * 32 + nf * 16 + lr;
                int sc = (ks * 4 + kg) ^ (R & 7);
                bfr[nf] = *(bf16x8*)&Bs[R * 64 + sc * 8];
            }
            #pragma unroll
            for (int mf = 0; mf < 4; mf++)
                #pragma unroll
                for (int nf = 0; nf < 2; nf++)
                    acc[mf][nf] = __builtin_amdgcn_mfma_f32_16x16x32_bf16(
                        af[mf], bfr[nf], acc[mf][nf], 0, 0, 0);
        }
        __syncthreads();
    }

    #pragma unroll
    for (int nf = 0; nf < 2; nf++) {
        int gc = bn + wc * 32 + nf * 16 + lr;
        float bvv = bias[gc];
        #pragma unroll
        for (int mf = 0; mf < 4; mf++) {
            int gr0 = bm + wr * 64 + mf * 16 + kg * 4;
            #pragma unroll
            for (int r = 0; r < 4; r++) {
                C[(size_t)(gr0 + r) * 256 + gc] = acc[mf][nf][r] + bvv;
            }
        }
    }
}

// ---------------------------------------------------------------------------
// Deformable sampling v7 (R9 best): fused softmax + tap table + 16B gathers,
// no manual pipelining. Block = 128 threads (2 waves) = 4 queries.
// ---------------------------------------------------------------------------
struct Acc8 {
    float a0, a1, a2, a3, a4, a5, a6, a7;
};

__device__ __forceinline__ void fma8(Acc8& acc, float wt, uint4 u) {
    acc.a0 = fmaf(wt, __uint_as_float(u.x << 16), acc.a0);
    acc.a1 = fmaf(wt, __uint_as_float(u.x & 0xffff0000u), acc.a1);
    acc.a2 = fmaf(wt, __uint_as_float(u.y << 16), acc.a2);
    acc.a3 = fmaf(wt, __uint_as_float(u.y & 0xffff0000u), acc.a3);
    acc.a4 = fmaf(wt, __uint_as_float(u.z << 16), acc.a4);
    acc.a5 = fmaf(wt, __uint_as_float(u.z & 0xffff0000u), acc.a5);
    acc.a6 = fmaf(wt, __uint_as_float(u.w << 16), acc.a6);
    acc.a7 = fmaf(wt, __uint_as_float(u.w & 0xffff0000u), acc.a7);
}

__global__ __launch_bounds__(128) void msda_sample_v7(
    const ushort* __restrict__ value, const float* __restrict__ comb,
    const float* __restrict__ refp, float* __restrict__ attn_out,
    ushort* __restrict__ out) {
    __shared__ int4   s_idx[4][8][13];   // [q][h][lp], pad 12->13
    __shared__ float4 s_w[4][8][13];
    int tid = threadIdx.x;
    int bq0 = blockIdx.x * 4;

    // ---- phase 1: softmax + tap setup (512 slots, 4 passes of 128) ----
    #pragma unroll
    for (int it = 0; it < 4; it++) {
        int t = tid + it * 128;
        int lp = t & 15;
        int qh = t >> 4;                 // 0..31
        int q = qh >> 3, h = qh & 7;
        int bq = bq0 + q;
        bool active = lp < 12;
        const float* crow = comb + (size_t)bq * 288;
        float logit = active ? crow[192 + h * 12 + lp] : -INFINITY;
        float m = logit;
        m = fmaxf(m, __shfl_xor(m, 1, 16));
        m = fmaxf(m, __shfl_xor(m, 2, 16));
        m = fmaxf(m, __shfl_xor(m, 4, 16));
        m = fmaxf(m, __shfl_xor(m, 8, 16));
        float e = active ? expf(logit - m) : 0.f;
        float s = e;
        s += __shfl_xor(s, 1, 16);
        s += __shfl_xor(s, 2, 16);
        s += __shfl_xor(s, 4, 16);
        s += __shfl_xor(s, 8, 16);
        float aw = e / s;
        if (active) {
            attn_out[(size_t)bq * 96 + h * 12 + lp] = aw;
            int l = lp >> 2;
            int b = bq / SEQ;
            int Wl = 64 >> l;
            float fW = (float)Wl;
            float rx = refp[(size_t)bq * 6 + 2 * l];
            float ry = refp[(size_t)bq * 6 + 2 * l + 1];
            float ox = crow[h * 24 + lp * 2];
            float oy = crow[h * 24 + lp * 2 + 1];
            float x = rx * fW + ox - 0.5f;
            float y = ry * fW + oy - 0.5f;
            float x0f = floorf(x), y0f = floorf(y);
            float wx = x - x0f, wy = y - y0f;
            int x0 = (int)x0f, y0 = (int)y0f;
            int x1 = x0 + 1, y1 = y0 + 1;
            float vx0 = (x0 >= 0 && x0 < Wl) ? 1.f : 0.f;
            float vx1 = (x1 >= 0 && x1 < Wl) ? 1.f : 0.f;
            float vy0 = (y0 >= 0 && y0 < Wl) ? 1.f : 0.f;   // square levels
            float vy1 = (y1 >= 0 && y1 < Wl) ? 1.f : 0.f;
            int xc0 = min(max(x0, 0), Wl - 1);
            int xc1 = min(max(x1, 0), Wl - 1);
            int yc0 = min(max(y0, 0), Wl - 1);
            int yc1 = min(max(y1, 0), Wl - 1);
            int st = (l == 0) ? 0 : ((l == 1) ? 4096 : 5120);
            int rowbase = b * SEQ + st;
            s_idx[q][h][lp] = make_int4((rowbase + yc0 * Wl + xc0) << 8,
                                        (rowbase + yc0 * Wl + xc1) << 8,
                                        (rowbase + yc1 * Wl + xc0) << 8,
                                        (rowbase + yc1 * Wl + xc1) << 8);
            s_w[q][h][lp] = make_float4(aw * (1.f - wx) * (1.f - wy) * vx0 * vy0,
                                        aw * wx * (1.f - wy) * vx1 * vy0,
                                        aw * (1.f - wx) * wy * vx0 * vy1,
                                        aw * wx * wy * vx1 * vy1);
        }
    }
    __syncthreads();

    // ---- phase 2: gather + FMA; 8 channels (16B) per lane ----
    int wave = tid >> 6, lane = tid & 63;
    int q2 = lane >> 5;
    int lane5 = lane & 31;
    int h = lane5 >> 2, d8 = lane5 & 3;
    int q = wave * 2 + q2;
    int bq = bq0 + q;
    int ch0 = h * 32 + d8 * 8;
    const ushort* vb = value + ch0;

    Acc8 acc = {0.f, 0.f, 0.f, 0.f, 0.f, 0.f, 0.f, 0.f};
    #pragma unroll
    for (int lp = 0; lp < 12; lp++) {
        int4 ii = s_idx[q][h][lp];
        float4 ww = s_w[q][h][lp];
        uint4 u0 = *(const uint4*)(vb + ii.x);
        uint4 u1 = *(const uint4*)(vb + ii.y);
        uint4 u2 = *(const uint4*)(vb + ii.z);
        uint4 u3 = *(const uint4*)(vb + ii.w);
        fma8(acc, ww.x, u0);
        fma8(acc, ww.y, u1);
        fma8(acc, ww.z, u2);
        fma8(acc, ww.w, u3);
    }

    bf16x8 o;
    o[0] = (short)f2b(acc.a0); o[1] = (short)f2b(acc.a1);
    o[2] = (short)f2b(acc.a2); o[3] = (short)f2b(acc.a3);
    o[4] = (short)f2b(acc.a4); o[5] = (short)f2b(acc.a5);
    o[6] = (short)f2b(acc.a6); o[7] = (short)f2b(acc.a7);
    *(bf16x8*)(out + (size_t)bq * 256 + ch0) = o;
}

// ---------------------------------------------------------------------------
extern "C" void kernel_launch(void* const* d_in, const int* in_sizes, int n_in,
                              void* d_out, int out_size, void* d_ws, size_t ws_size,
                              hipStream_t stream) {
    const float* hidden = (const float*)d_in[0];
    const float* pos    = (const float*)d_in[1];
    const float* refp   = (const float*)d_in[2];
    const float* Wv     = (const float*)d_in[3];
    const float* bv     = (const float*)d_in[4];
    const float* Wo     = (const float*)d_in[5];
    const float* bo     = (const float*)d_in[6];
    const float* Wa     = (const float*)d_in[7];
    const float* ba     = (const float*)d_in[8];
    const float* Wout   = (const float*)d_in[9];
    const float* bout   = (const float*)d_in[10];

    float* out      = (float*)d_out;                       // (B,SEQ,256)
    float* attn_out = out + (size_t)BB * SEQ * DD;         // (B,SEQ,NH,NL,NP)

    const size_t BSD = (size_t)BB * SEQ * DD;              // 5,505,024
    char* w = (char*)d_ws;
    ushort* value_bf = (ushort*)w;  w += BSD * 2;                 // bf16 value
    float*  comb     = (float*)w;   w += (size_t)MTOT * 288 * 4;  // off|logits
    ushort* sampb    = (ushort*)w;  w += BSD * 2;                 // bf16 sampled
    ushort* hb       = (ushort*)w;  w += BSD * 2;                 // bf16 hidden
    ushort* hsb      = (ushort*)w;  w += BSD * 2;                 // bf16 hidden+pos
    ushort* Wt       = (ushort*)w;  w += (size_t)800 * 256 * 2;   // bf16 weights^T
    float*  bcomb    = (float*)w;                                 // 288 bias

    // 1. fused prep: weights transpose + activation bf16 conversion
    {
        int n4 = (int)(BSD / 4);
        prep_all<<<801 + 2048, 256, 0, stream>>>(hidden, pos, Wv, Wo, Wa, Wout,
                                                 bo, ba, (ushort4*)hb, (ushort4*)hsb,
                                                 Wt, bcomb, n4);
    }

    const ushort* Wv_t    = Wt;
    const ushort* Wcomb_t = Wt + (size_t)256 * 256;   // rows: 192 Wo + 96 Wa
    const ushort* Wout_t  = Wt + (size_t)544 * 256;

    // 2. fused value+comb GEMMs (840 blocks for grid fill)
    gemm_dual<<<840, 256, 0, stream>>>(hb, hsb, Wv_t, Wcomb_t, bv, bcomb,
                                       value_bf, comb);

    // 3. fused softmax + deformable sampling -> attn_out + sampled bf16
    msda_sample_v7<<<MTOT / 4, 128, 0, stream>>>(value_bf, comb, refp,
                                                 attn_out, sampb);

    // 4. out = sampled @ Wout + bout -> d_out (BN=64: 672 blocks)
    {
        dim3 grid(DD / 64, MTOT / 128);
        gemm_out<<<grid, 256, 0, stream>>>(sampb, Wout_t, bout, out);
    }
}

// Round 15
// 80.495 us; speedup vs baseline: 3.2491x; 1.0237x over previous
//
#include <hip/hip_runtime.h>
#include <hip/hip_bf16.h>
#include <math.h>

// Problem constants (Mask2Former pixel decoder / MS-deformable attention)
#define BB 4
#define SEQ 5376
#define DD 256
#define NH 8
#define NL 3
#define NP 4
#define DH 32
#define MTOT (BB * SEQ)          // 21504 rows for all GEMMs

typedef __attribute__((ext_vector_type(8))) short bf16x8;
typedef __attribute__((ext_vector_type(4))) float f32x4;
typedef __attribute__((ext_vector_type(2))) float f32x2;

#define GLD_LDS16(src, dst) __builtin_amdgcn_global_load_lds( \
    (const __attribute__((address_space(1))) void*)(src),     \
    (__attribute__((address_space(3))) void*)(dst), 16, 0, 0)

__device__ __forceinline__ ushort f2b(float f) {
    __hip_bfloat16 h = __float2bfloat16(f);
    return *reinterpret_cast<ushort*>(&h);
}

// ---------------------------------------------------------------------------
// Fused prep: blocks [0,800] transpose weights -> Wt[800][256] bf16 (+bias
// combine at block 800); blocks [801, 801+2048) convert hidden -> bf16 and
// (hidden+pos) -> bf16 (grid-stride).
// ---------------------------------------------------------------------------
__global__ __launch_bounds__(256) void prep_all(
    const float* __restrict__ hidden, const float* __restrict__ pos,
    const float* __restrict__ Wv, const float* __restrict__ Wo,
    const float* __restrict__ Wa, const float* __restrict__ Wout,
    const float* __restrict__ bo, const float* __restrict__ ba,
    ushort4* __restrict__ hb, ushort4* __restrict__ hsb,
    ushort* __restrict__ Wt, float* __restrict__ bcomb, int n4) {
    int bid = blockIdx.x;
    int tid = threadIdx.x;
    if (bid <= 800) {
        if (bid == 800) {
            for (int i = tid; i < 288; i += 256)
                bcomb[i] = (i < 192) ? bo[i] : ba[i - 192];
            return;
        }
        int row = bid;
        const float* src;
        int N, n;
        if (row < 256)      { src = Wv;   N = 256; n = row; }
        else if (row < 448) { src = Wo;   N = 192; n = row - 256; }
        else if (row < 544) { src = Wa;   N = 96;  n = row - 448; }
        else                { src = Wout; N = 256; n = row - 544; }
        float v = src[(size_t)tid * N + n];
        Wt[(size_t)row * 256 + tid] = f2b(v);
        return;
    }
    // activation conversion
    const float4* h4 = (const float4*)hidden;
    const float4* p4 = (const float4*)pos;
    int i = (bid - 801) * 256 + tid;
    int stride = (gridDim.x - 801) * 256;
    for (; i < n4; i += stride) {
        float4 a = h4[i], b = p4[i];
        ushort4 ua, us;
        ua.x = f2b(a.x); ua.y = f2b(a.y); ua.z = f2b(a.z); ua.w = f2b(a.w);
        us.x = f2b(a.x + b.x); us.y = f2b(a.y + b.y);
        us.z = f2b(a.z + b.z); us.w = f2b(a.w + b.w);
        hb[i] = ua;
        hsb[i] = us;
    }
}

// ---------------------------------------------------------------------------
// Dual bf16 MFMA GEMM (one dispatch = value GEMM + comb GEMM for grid fill).
// Blocks [0,336): value = hb @ Wv^T + bv -> bf16, N=256 (2 col-blocks x 168).
// Blocks [336,840): comb = hsb @ Wcomb^T + bcomb -> fp32, N=288 (3 x 168).
// BM=128, BN=128, BK=64; global_load_lds staging, chunk-XOR swizzle both
// sides (R13-proven). 256 thr = 4 waves 2x2; 32 MFMA/wave per barrier pair.
// ---------------------------------------------------------------------------
__global__ __launch_bounds__(256) void gemm_dual(
    const ushort* __restrict__ hb, const ushort* __restrict__ hsb,
    const ushort* __restrict__ Wv_t, const ushort* __restrict__ Wcomb_t,
    const float* __restrict__ bv, const float* __restrict__ bcomb,
    ushort* __restrict__ value_bf, float* __restrict__ comb) {
    const int K = 256, BK = 64;
    __shared__ ushort As[128 * 64];
    __shared__ ushort Bs[128 * 64];

    int b = blockIdx.x;
    const ushort* A;
    const ushort* W;
    const float* bias;
    int bn, bm, N;
    bool obf;
    if (b < 336) {
        A = hb;  W = Wv_t;    bias = bv;    N = 256; obf = true;
        bn = (b & 1) * 128;   bm = (b >> 1) * 128;
    } else {
        int bb = b - 336;
        A = hsb; W = Wcomb_t; bias = bcomb; N = 288; obf = false;
        bn = (bb % 3) * 128;  bm = (bb / 3) * 128;
    }

    int tid = threadIdx.x;
    int lane = tid & 63;
    int wid = tid >> 6;
    int wr = wid >> 1, wc = wid & 1;
    int lr = lane & 15;
    int kg = lane >> 4;

    f32x4 acc[4][4] = {};

    for (int k0 = 0; k0 < K; k0 += BK) {
        #pragma unroll
        for (int c = 0; c < 4; c++) {
            int e = tid + 256 * c;           // chunk id 0..1023
            int row = e >> 3;
            int ch = e & 7;
            int gch = ch ^ (row & 7);
            GLD_LDS16(A + (size_t)(bm + row) * K + k0 + 8 * gch, &As[e * 8]);
            GLD_LDS16(W + (size_t)(bn + row) * K + k0 + 8 * gch, &Bs[e * 8]);
        }
        __syncthreads();
        #pragma unroll
        for (int ks = 0; ks < 2; ks++) {
            bf16x8 af[4], bfr[4];
            #pragma unroll
            for (int mf = 0; mf < 4; mf++) {
                int R = wr * 64 + mf * 16 + lr;
                int sc = (ks * 4 + kg) ^ (R & 7);
                af[mf] = *(bf16x8*)&As[R * 64 + sc * 8];
            }
            #pragma unroll
            for (int nf = 0; nf < 4; nf++) {
                int R = wc * 64 + nf * 16 + lr;
                int sc = (ks * 4 + kg) ^ (R & 7);
                bfr[nf] = *(bf16x8*)&Bs[R * 64 + sc * 8];
            }
            #pragma unroll
            for (int mf = 0; mf < 4; mf++)
                #pragma unroll
                for (int nf = 0; nf < 4; nf++)
                    acc[mf][nf] = __builtin_amdgcn_mfma_f32_16x16x32_bf16(
                        af[mf], bfr[nf], acc[mf][nf], 0, 0, 0);
        }
        __syncthreads();
    }

    #pragma unroll
    for (int nf = 0; nf < 4; nf++) {
        int gc = bn + wc * 64 + nf * 16 + lr;
        if (gc >= N) continue;
        float bvv = bias[gc];
        #pragma unroll
        for (int mf = 0; mf < 4; mf++) {
            int gr0 = bm + wr * 64 + mf * 16 + kg * 4;
            #pragma unroll
            for (int r = 0; r < 4; r++) {
                float v = acc[mf][nf][r] + bvv;
                if (obf)
                    value_bf[(size_t)(gr0 + r) * 256 + gc] = f2b(v);
                else
                    comb[(size_t)(gr0 + r) * 288 + gc] = v;
            }
        }
    }
}

// ---------------------------------------------------------------------------
// Output GEMM: out = sampb @ Wout^T + bout, N=256, fp32 out.
// BM=128, BN=64 (672 blocks for grid fill), BK=64; gld_lds + XOR swizzle.
// ---------------------------------------------------------------------------
__global__ __launch_bounds__(256) void gemm_out(
    const ushort* __restrict__ A, const ushort* __restrict__ Wt,
    const float* __restrict__ bias, float* __restrict__ C) {
    const int K = 256, BK = 64;
    __shared__ ushort As[128 * 64];
    __shared__ ushort Bs[64 * 64];
    int bm = blockIdx.y * 128;
    int bn = blockIdx.x * 64;
    int tid = threadIdx.x;
    int lane = tid & 63;
    int wid = tid >> 6;
    int wr = wid >> 1, wc = wid & 1;
    int lr = lane & 15;
    int kg = lane >> 4;

    f32x4 acc[4][2] = {};

    for (int k0 = 0; k0 < K; k0 += BK) {
        #pragma unroll
        for (int c = 0; c < 4; c++) {
            int e = tid + 256 * c;
            int row = e >> 3;
            int ch = e & 7;
            int gch = ch ^ (row & 7);
            GLD_LDS16(A + (size_t)(bm + row) * K + k0 + 8 * gch, &As[e * 8]);
        }
        #pragma unroll
        for (int c = 0; c < 2; c++) {
            int e = tid + 256 * c;           // 0..511
            int row = e >> 3;                // 0..63
            int ch = e & 7;
            int gch = ch ^ (row & 7);
            GLD_LDS16(Wt + (size_t)(bn + row) * K + k0 + 8 * gch, &Bs[e * 8]);
        }
        __syncthreads();
        #pragma unroll
        for (int ks = 0; ks < 2; ks++) {
            bf16x8 af[4], bfr[2];
            #pragma unroll
            for (int mf = 0; mf < 4; mf++) {
                int R = wr * 64 + mf * 16 + lr;
                int sc = (ks * 4 + kg) ^ (R & 7);
                af[mf] = *(bf16x8*)&As[R * 64 + sc * 8];
            }
            #pragma unroll
            for (int nf = 0; nf < 2; nf++) {
                int R = wc * 32 + nf * 16 + lr;
                int sc = (ks * 4 + kg) ^ (R & 7);
                bfr[nf] = *(bf16x8*)&Bs[R * 64 + sc * 8];
            }
            #pragma unroll
            for (int mf = 0; mf < 4; mf++)
                #pragma unroll
                for (int nf = 0; nf < 2; nf++)
                    acc[mf][nf] = __builtin_amdgcn_mfma_f32_16x16x32_bf16(
                        af[mf], bfr[nf], acc[mf][nf], 0, 0, 0);
        }
        __syncthreads();
    }

    #pragma unroll
    for (int nf = 0; nf < 2; nf++) {
        int gc = bn + wc * 32 + nf * 16 + lr;
        float bvv = bias[gc];
        #pragma unroll
        for (int mf = 0; mf < 4; mf++) {
            int gr0 = bm + wr * 64 + mf * 16 + kg * 4;
            #pragma unroll
            for (int r = 0; r < 4; r++) {
                C[(size_t)(gr0 + r) * 256 + gc] = acc[mf][nf][r] + bvv;
            }
        }
    }
}

// ---------------------------------------------------------------------------
// Deformable sampling v11: v7 structure + packed-pair FMA (v_pk_fma_f32).
// Block = 128 threads (2 waves) = 4 queries; 8 channels (16B gathers)/lane.
// Channel math as float2 vectors -> compiler emits VOP3P packed FMAs,
// halving the fma instruction count (24 -> ~12 VALU per gather).
// ---------------------------------------------------------------------------
__device__ __forceinline__ void fma8p(f32x2 acc[4], float wt, uint4 u) {
    f32x2 w2 = {wt, wt};
    uint p0 = u.x, p1 = u.y, p2 = u.z, p3 = u.w;
    f32x2 v0, v1, v2, v3;
    v0[0] = __uint_as_float(p0 << 16); v0[1] = __uint_as_float(p0 & 0xffff0000u);
    v1[0] = __uint_as_float(p1 << 16); v1[1] = __uint_as_float(p1 & 0xffff0000u);
    v2[0] = __uint_as_float(p2 << 16); v2[1] = __uint_as_float(p2 & 0xffff0000u);
    v3[0] = __uint_as_float(p3 << 16); v3[1] = __uint_as_float(p3 & 0xffff0000u);
    acc[0] = __builtin_elementwise_fma(v0, w2, acc[0]);
    acc[1] = __builtin_elementwise_fma(v1, w2, acc[1]);
    acc[2] = __builtin_elementwise_fma(v2, w2, acc[2]);
    acc[3] = __builtin_elementwise_fma(v3, w2, acc[3]);
}

__global__ __launch_bounds__(128) void msda_sample_v11(
    const ushort* __restrict__ value, const float* __restrict__ comb,
    const float* __restrict__ refp, float* __restrict__ attn_out,
    ushort* __restrict__ out) {
    __shared__ int4   s_idx[4][8][13];   // [q][h][lp], pad 12->13
    __shared__ float4 s_w[4][8][13];
    int tid = threadIdx.x;
    int bq0 = blockIdx.x * 4;

    // ---- phase 1: softmax + tap setup (512 slots, 4 passes of 128) ----
    #pragma unroll
    for (int it = 0; it < 4; it++) {
        int t = tid + it * 128;
        int lp = t & 15;
        int qh = t >> 4;                 // 0..31
        int q = qh >> 3, h = qh & 7;
        int bq = bq0 + q;
        bool active = lp < 12;
        const float* crow = comb + (size_t)bq * 288;
        float logit = active ? crow[192 + h * 12 + lp] : -INFINITY;
        float m = logit;
        m = fmaxf(m, __shfl_xor(m, 1, 16));
        m = fmaxf(m, __shfl_xor(m, 2, 16));
        m = fmaxf(m, __shfl_xor(m, 4, 16));
        m = fmaxf(m, __shfl_xor(m, 8, 16));
        float e = active ? expf(logit - m) : 0.f;
        float s = e;
        s += __shfl_xor(s, 1, 16);
        s += __shfl_xor(s, 2, 16);
        s += __shfl_xor(s, 4, 16);
        s += __shfl_xor(s, 8, 16);
        float aw = e / s;
        if (active) {
            attn_out[(size_t)bq * 96 + h * 12 + lp] = aw;
            int l = lp >> 2;
            int b = bq / SEQ;
            int Wl = 64 >> l;
            float fW = (float)Wl;
            float rx = refp[(size_t)bq * 6 + 2 * l];
            float ry = refp[(size_t)bq * 6 + 2 * l + 1];
            float ox = crow[h * 24 + lp * 2];
            float oy = crow[h * 24 + lp * 2 + 1];
            float x = rx * fW + ox - 0.5f;
            float y = ry * fW + oy - 0.5f;
            float x0f = floorf(x), y0f = floorf(y);
            float wx = x - x0f, wy = y - y0f;
            int x0 = (int)x0f, y0 = (int)y0f;
            int x1 = x0 + 1, y1 = y0 + 1;
            float vx0 = (x0 >= 0 && x0 < Wl) ? 1.f : 0.f;
            float vx1 = (x1 >= 0 && x1 < Wl) ? 1.f : 0.f;
            float vy0 = (y0 >= 0 && y0 < Wl) ? 1.f : 0.f;   // square levels
            float vy1 = (y1 >= 0 && y1 < Wl) ? 1.f : 0.f;
            int xc0 = min(max(x0, 0), Wl - 1);
            int xc1 = min(max(x1, 0), Wl - 1);
            int yc0 = min(max(y0, 0), Wl - 1);
            int yc1 = min(max(y1, 0), Wl - 1);
            int st = (l == 0) ? 0 : ((l == 1) ? 4096 : 5120);
            int rowbase = b * SEQ + st;
            s_idx[q][h][lp] = make_int4((rowbase + yc0 * Wl + xc0) << 8,
                                        (rowbase + yc0 * Wl + xc1) << 8,
                                        (rowbase + yc1 * Wl + xc0) << 8,
                                        (rowbase + yc1 * Wl + xc1) << 8);
            s_w[q][h][lp] = make_float4(aw * (1.f - wx) * (1.f - wy) * vx0 * vy0,
                                        aw * wx * (1.f - wy) * vx1 * vy0,
                                        aw * (1.f - wx) * wy * vx0 * vy1,
                                        aw * wx * wy * vx1 * vy1);
        }
    }
    __syncthreads();

    // ---- phase 2: gather + packed FMA; 8 channels (16B) per lane ----
    int wave = tid >> 6, lane = tid & 63;
    int q2 = lane >> 5;
    int lane5 = lane & 31;
    int h = lane5 >> 2, d8 = lane5 & 3;
    int q = wave * 2 + q2;
    int bq = bq0 + q;
    int ch0 = h * 32 + d8 * 8;
    const ushort* vb = value + ch0;

    f32x2 acc[4] = {{0.f, 0.f}, {0.f, 0.f}, {0.f, 0.f}, {0.f, 0.f}};
    #pragma unroll
    for (int lp = 0; lp < 12; lp++) {
        int4 ii = s_idx[q][h][lp];
        float4 ww = s_w[q][h][lp];
        uint4 u0 = *(const uint4*)(vb + ii.x);
        uint4 u1 = *(const uint4*)(vb + ii.y);
        uint4 u2 = *(const uint4*)(vb + ii.z);
        uint4 u3 = *(const uint4*)(vb + ii.w);
        fma8p(acc, ww.x, u0);
        fma8p(acc, ww.y, u1);
        fma8p(acc, ww.z, u2);
        fma8p(acc, ww.w, u3);
    }

    bf16x8 o;
    o[0] = (short)f2b(acc[0][0]); o[1] = (short)f2b(acc[0][1]);
    o[2] = (short)f2b(acc[1][0]); o[3] = (short)f2b(acc[1][1]);
    o[4] = (short)f2b(acc[2][0]); o[5] = (short)f2b(acc[2][1]);
    o[6] = (short)f2b(acc[3][0]); o[7] = (short)f2b(acc[3][1]);
    *(bf16x8*)(out + (size_t)bq * 256 + ch0) = o;
}

// ---------------------------------------------------------------------------
extern "C" void kernel_launch(void* const* d_in, const int* in_sizes, int n_in,
                              void* d_out, int out_size, void* d_ws, size_t ws_size,
                              hipStream_t stream) {
    const float* hidden = (const float*)d_in[0];
    const float* pos    = (const float*)d_in[1];
    const float* refp   = (const float*)d_in[2];
    const float* Wv     = (const float*)d_in[3];
    const float* bv     = (const float*)d_in[4];
    const float* Wo     = (const float*)d_in[5];
    const float* bo     = (const float*)d_in[6];
    const float* Wa     = (const float*)d_in[7];
    const float* ba     = (const float*)d_in[8];
    const float* Wout   = (const float*)d_in[9];
    const float* bout   = (const float*)d_in[10];

    float* out      = (float*)d_out;                       // (B,SEQ,256)
    float* attn_out = out + (size_t)BB * SEQ * DD;         // (B,SEQ,NH,NL,NP)

    const size_t BSD = (size_t)BB * SEQ * DD;              // 5,505,024
    char* w = (char*)d_ws;
    ushort* value_bf = (ushort*)w;  w += BSD * 2;                 // bf16 value
    float*  comb     = (float*)w;   w += (size_t)MTOT * 288 * 4;  // off|logits
    ushort* sampb    = (ushort*)w;  w += BSD * 2;                 // bf16 sampled
    ushort* hb       = (ushort*)w;  w += BSD * 2;                 // bf16 hidden
    ushort* hsb      = (ushort*)w;  w += BSD * 2;                 // bf16 hidden+pos
    ushort* Wt       = (ushort*)w;  w += (size_t)800 * 256 * 2;   // bf16 weights^T
    float*  bcomb    = (float*)w;                                 // 288 bias

    // 1. fused prep: weights transpose + activation bf16 conversion
    {
        int n4 = (int)(BSD / 4);
        prep_all<<<801 + 2048, 256, 0, stream>>>(hidden, pos, Wv, Wo, Wa, Wout,
                                                 bo, ba, (ushort4*)hb, (ushort4*)hsb,
                                                 Wt, bcomb, n4);
    }

    const ushort* Wv_t    = Wt;
    const ushort* Wcomb_t = Wt + (size_t)256 * 256;   // rows: 192 Wo + 96 Wa
    const ushort* Wout_t  = Wt + (size_t)544 * 256;

    // 2. fused value+comb GEMMs (840 blocks for grid fill)
    gemm_dual<<<840, 256, 0, stream>>>(hb, hsb, Wv_t, Wcomb_t, bv, bcomb,
                                       value_bf, comb);

    // 3. fused softmax + deformable sampling -> attn_out + sampled bf16
    msda_sample_v11<<<MTOT / 4, 128, 0, stream>>>(value_bf, comb, refp,
                                                  attn_out, sampb);

    // 4. out = sampled @ Wout + bout -> d_out (BN=64: 672 blocks)
    {
        dim3 grid(DD / 64, MTOT / 128);
        gemm_out<<<grid, 256, 0, stream>>>(sampb, Wout_t, bout, out);
    }
}

// Round 16
// 78.227 us; speedup vs baseline: 3.3433x; 1.0290x over previous
//
#include <hip/hip_runtime.h>
#include <hip/hip_bf16.h>
#include <math.h>

// Problem constants (Mask2Former pixel decoder / MS-deformable attention)
#define BB 4
#define SEQ 5376
#define DD 256
#define NH 8
#define NL 3
#define NP 4
#define DH 32
#define MTOT (BB * SEQ)          // 21504 rows for all GEMMs

typedef __attribute__((ext_vector_type(8))) short bf16x8;
typedef __attribute__((ext_vector_type(4))) float f32x4;
typedef __attribute__((ext_vector_type(2))) float f32x2;

#define GLD_LDS16(src, dst) __builtin_amdgcn_global_load_lds( \
    (const __attribute__((address_space(1))) void*)(src),     \
    (__attribute__((address_space(3))) void*)(dst), 16, 0, 0)

__device__ __forceinline__ ushort f2b(float f) {
    __hip_bfloat16 h = __float2bfloat16(f);
    return *reinterpret_cast<ushort*>(&h);
}

// ---------------------------------------------------------------------------
// Fused prep: blocks [0,800] transpose weights -> Wt[800][256] bf16 (+bias
// combine at block 800); blocks [801, 801+2048) convert hidden -> bf16 and
// (hidden+pos) -> bf16 (grid-stride).
// ---------------------------------------------------------------------------
__global__ __launch_bounds__(256) void prep_all(
    const float* __restrict__ hidden, const float* __restrict__ pos,
    const float* __restrict__ Wv, const float* __restrict__ Wo,
    const float* __restrict__ Wa, const float* __restrict__ Wout,
    const float* __restrict__ bo, const float* __restrict__ ba,
    ushort4* __restrict__ hb, ushort4* __restrict__ hsb,
    ushort* __restrict__ Wt, float* __restrict__ bcomb, int n4) {
    int bid = blockIdx.x;
    int tid = threadIdx.x;
    if (bid <= 800) {
        if (bid == 800) {
            for (int i = tid; i < 288; i += 256)
                bcomb[i] = (i < 192) ? bo[i] : ba[i - 192];
            return;
        }
        int row = bid;
        const float* src;
        int N, n;
        if (row < 256)      { src = Wv;   N = 256; n = row; }
        else if (row < 448) { src = Wo;   N = 192; n = row - 256; }
        else if (row < 544) { src = Wa;   N = 96;  n = row - 448; }
        else                { src = Wout; N = 256; n = row - 544; }
        float v = src[(size_t)tid * N + n];
        Wt[(size_t)row * 256 + tid] = f2b(v);
        return;
    }
    // activation conversion
    const float4* h4 = (const float4*)hidden;
    const float4* p4 = (const float4*)pos;
    int i = (bid - 801) * 256 + tid;
    int stride = (gridDim.x - 801) * 256;
    for (; i < n4; i += stride) {
        float4 a = h4[i], b = p4[i];
        ushort4 ua, us;
        ua.x = f2b(a.x); ua.y = f2b(a.y); ua.z = f2b(a.z); ua.w = f2b(a.w);
        us.x = f2b(a.x + b.x); us.y = f2b(a.y + b.y);
        us.z = f2b(a.z + b.z); us.w = f2b(a.w + b.w);
        hb[i] = ua;
        hsb[i] = us;
    }
}

// ---------------------------------------------------------------------------
// Dual bf16 MFMA GEMM (one dispatch = value GEMM + comb GEMM for grid fill).
// Blocks [0,336): value = hb @ Wv^T + bv -> bf16 HEAD-MAJOR [h][row][32ch].
// Blocks [336,840): comb = hsb @ Wcomb^T + bcomb -> fp32, N=288.
// BM=128, BN=128, BK=64; global_load_lds staging, chunk-XOR swizzle both
// sides (R13-proven). 256 thr = 4 waves 2x2; 32 MFMA/wave per barrier pair.
// ---------------------------------------------------------------------------
__global__ __launch_bounds__(256) void gemm_dual(
    const ushort* __restrict__ hb, const ushort* __restrict__ hsb,
    const ushort* __restrict__ Wv_t, const ushort* __restrict__ Wcomb_t,
    const float* __restrict__ bv, const float* __restrict__ bcomb,
    ushort* __restrict__ value_bf, float* __restrict__ comb) {
    const int K = 256, BK = 64;
    __shared__ ushort As[128 * 64];
    __shared__ ushort Bs[128 * 64];

    int b = blockIdx.x;
    const ushort* A;
    const ushort* W;
    const float* bias;
    int bn, bm, N;
    bool obf;
    if (b < 336) {
        A = hb;  W = Wv_t;    bias = bv;    N = 256; obf = true;
        bn = (b & 1) * 128;   bm = (b >> 1) * 128;
    } else {
        int bb = b - 336;
        A = hsb; W = Wcomb_t; bias = bcomb; N = 288; obf = false;
        bn = (bb % 3) * 128;  bm = (bb / 3) * 128;
    }

    int tid = threadIdx.x;
    int lane = tid & 63;
    int wid = tid >> 6;
    int wr = wid >> 1, wc = wid & 1;
    int lr = lane & 15;
    int kg = lane >> 4;

    f32x4 acc[4][4] = {};

    for (int k0 = 0; k0 < K; k0 += BK) {
        #pragma unroll
        for (int c = 0; c < 4; c++) {
            int e = tid + 256 * c;           // chunk id 0..1023
            int row = e >> 3;
            int ch = e & 7;
            int gch = ch ^ (row & 7);
            GLD_LDS16(A + (size_t)(bm + row) * K + k0 + 8 * gch, &As[e * 8]);
            GLD_LDS16(W + (size_t)(bn + row) * K + k0 + 8 * gch, &Bs[e * 8]);
        }
        __syncthreads();
        #pragma unroll
        for (int ks = 0; ks < 2; ks++) {
            bf16x8 af[4], bfr[4];
            #pragma unroll
            for (int mf = 0; mf < 4; mf++) {
                int R = wr * 64 + mf * 16 + lr;
                int sc = (ks * 4 + kg) ^ (R & 7);
                af[mf] = *(bf16x8*)&As[R * 64 + sc * 8];
            }
            #pragma unroll
            for (int nf = 0; nf < 4; nf++) {
                int R = wc * 64 + nf * 16 + lr;
                int sc = (ks * 4 + kg) ^ (R & 7);
                bfr[nf] = *(bf16x8*)&Bs[R * 64 + sc * 8];
            }
            #pragma unroll
            for (int mf = 0; mf < 4; mf++)
                #pragma unroll
                for (int nf = 0; nf < 4; nf++)
                    acc[mf][nf] = __builtin_amdgcn_mfma_f32_16x16x32_bf16(
                        af[mf], bfr[nf], acc[mf][nf], 0, 0, 0);
        }
        __syncthreads();
    }

    #pragma unroll
    for (int nf = 0; nf < 4; nf++) {
        int gc = bn + wc * 64 + nf * 16 + lr;
        if (gc >= N) continue;
        float bvv = bias[gc];
        #pragma unroll
        for (int mf = 0; mf < 4; mf++) {
            int gr0 = bm + wr * 64 + mf * 16 + kg * 4;
            #pragma unroll
            for (int r = 0; r < 4; r++) {
                float v = acc[mf][nf][r] + bvv;
                if (obf) {
                    // head-major scatter: [h][row][32ch]
                    int hh = gc >> 5, cc = gc & 31;
                    value_bf[(size_t)hh * ((size_t)MTOT * 32)
                             + (size_t)(gr0 + r) * 32 + cc] = f2b(v);
                } else {
                    comb[(size_t)(gr0 + r) * 288 + gc] = v;
                }
            }
        }
    }
}

// ---------------------------------------------------------------------------
// Output GEMM: out = sampb @ Wout^T + bout, N=256, fp32 out.
// BM=128, BN=64 (672 blocks for grid fill), BK=64; gld_lds + XOR swizzle.
// ---------------------------------------------------------------------------
__global__ __launch_bounds__(256) void gemm_out(
    const ushort* __restrict__ A, const ushort* __restrict__ Wt,
    const float* __restrict__ bias, float* __restrict__ C) {
    const int K = 256, BK = 64;
    __shared__ ushort As[128 * 64];
    __shared__ ushort Bs[64 * 64];
    int bm = blockIdx.y * 128;
    int bn = blockIdx.x * 64;
    int tid = threadIdx.x;
    int lane = tid & 63;
    int wid = tid >> 6;
    int wr = wid >> 1, wc = wid & 1;
    int lr = lane & 15;
    int kg = lane >> 4;

    f32x4 acc[4][2] = {};

    for (int k0 = 0; k0 < K; k0 += BK) {
        #pragma unroll
        for (int c = 0; c < 4; c++) {
            int e = tid + 256 * c;
            int row = e >> 3;
            int ch = e & 7;
            int gch = ch ^ (row & 7);
            GLD_LDS16(A + (size_t)(bm + row) * K + k0 + 8 * gch, &As[e * 8]);
        }
        #pragma unroll
        for (int c = 0; c < 2; c++) {
            int e = tid + 256 * c;           // 0..511
            int row = e >> 3;                // 0..63
            int ch = e & 7;
            int gch = ch ^ (row & 7);
            GLD_LDS16(Wt + (size_t)(bn + row) * K + k0 + 8 * gch, &Bs[e * 8]);
        }
        __syncthreads();
        #pragma unroll
        for (int ks = 0; ks < 2; ks++) {
            bf16x8 af[4], bfr[2];
            #pragma unroll
            for (int mf = 0; mf < 4; mf++) {
                int R = wr * 64 + mf * 16 + lr;
                int sc = (ks * 4 + kg) ^ (R & 7);
                af[mf] = *(bf16x8*)&As[R * 64 + sc * 8];
            }
            #pragma unroll
            for (int nf = 0; nf < 2; nf++) {
                int R = wc * 32 + nf * 16 + lr;
                int sc = (ks * 4 + kg) ^ (R & 7);
                bfr[nf] = *(bf16x8*)&Bs[R * 64 + sc * 8];
            }
            #pragma unroll
            for (int mf = 0; mf < 4; mf++)
                #pragma unroll
                for (int nf = 0; nf < 2; nf++)
                    acc[mf][nf] = __builtin_amdgcn_mfma_f32_16x16x32_bf16(
                        af[mf], bfr[nf], acc[mf][nf], 0, 0, 0);
        }
        __syncthreads();
    }

    #pragma unroll
    for (int nf = 0; nf < 2; nf++) {
        int gc = bn + wc * 32 + nf * 16 + lr;
        float bvv = bias[gc];
        #pragma unroll
        for (int mf = 0; mf < 4; mf++) {
            int gr0 = bm + wr * 64 + mf * 16 + kg * 4;
            #pragma unroll
            for (int r = 0; r < 4; r++) {
                C[(size_t)(gr0 + r) * 256 + gc] = acc[mf][nf][r] + bvv;
            }
        }
    }
}

// ---------------------------------------------------------------------------
// Deformable sampling v12: head-major value + x-pair loads.
// Block = 128 threads = 2 waves = 2 queries (wave = query).
// Lane = h*8 + d8; part = d8>>2 selects x-slot {px, px+1}; c4 = d8&3 the
// channel quad (8 ch, 16B). Per tap: 2 loads (y0-pair-row, y1-pair-row),
// 128B-contiguous per (h, row); shfl_xor(4) combines the x-parts at the end.
// All loads in-bounds: pair base px = clamp(x0, 0, Wl-2).
// ---------------------------------------------------------------------------
__device__ __forceinline__ void fma8p(f32x2 acc[4], float wt, uint4 u) {
    f32x2 w2 = {wt, wt};
    f32x2 v0, v1, v2, v3;
    v0[0] = __uint_as_float(u.x << 16); v0[1] = __uint_as_float(u.x & 0xffff0000u);
    v1[0] = __uint_as_float(u.y << 16); v1[1] = __uint_as_float(u.y & 0xffff0000u);
    v2[0] = __uint_as_float(u.z << 16); v2[1] = __uint_as_float(u.z & 0xffff0000u);
    v3[0] = __uint_as_float(u.w << 16); v3[1] = __uint_as_float(u.w & 0xffff0000u);
    acc[0] = __builtin_elementwise_fma(v0, w2, acc[0]);
    acc[1] = __builtin_elementwise_fma(v1, w2, acc[1]);
    acc[2] = __builtin_elementwise_fma(v2, w2, acc[2]);
    acc[3] = __builtin_elementwise_fma(v3, w2, acc[3]);
}

__global__ __launch_bounds__(128) void msda_sample_v12(
    const ushort* __restrict__ value, const float* __restrict__ comb,
    const float* __restrict__ refp, float* __restrict__ attn_out,
    ushort* __restrict__ out) {
    __shared__ int2   s_idx[2][8][13];   // [q][h][lp]: row offsets (elements)
    __shared__ float4 s_w[2][8][13];     // (wA_y0, wB_y0, wA_y1, wB_y1)
    int tid = threadIdx.x;
    int bq0 = blockIdx.x * 2;

    // ---- phase 1: softmax + tap setup (256 slots, 2 passes of 128) ----
    #pragma unroll
    for (int it = 0; it < 2; it++) {
        int t = tid + it * 128;
        int lp = t & 15;
        int qh = t >> 4;                 // 0..15
        int q = qh >> 3, h = qh & 7;
        int bq = bq0 + q;
        bool active = lp < 12;
        const float* crow = comb + (size_t)bq * 288;
        float logit = active ? crow[192 + h * 12 + lp] : -INFINITY;
        float m = logit;
        m = fmaxf(m, __shfl_xor(m, 1, 16));
        m = fmaxf(m, __shfl_xor(m, 2, 16));
        m = fmaxf(m, __shfl_xor(m, 4, 16));
        m = fmaxf(m, __shfl_xor(m, 8, 16));
        float e = active ? expf(logit - m) : 0.f;
        float s = e;
        s += __shfl_xor(s, 1, 16);
        s += __shfl_xor(s, 2, 16);
        s += __shfl_xor(s, 4, 16);
        s += __shfl_xor(s, 8, 16);
        float aw = e / s;
        if (active) {
            attn_out[(size_t)bq * 96 + h * 12 + lp] = aw;
            int l = lp >> 2;
            int b = bq / SEQ;
            int Wl = 64 >> l;
            float fW = (float)Wl;
            float rx = refp[(size_t)bq * 6 + 2 * l];
            float ry = refp[(size_t)bq * 6 + 2 * l + 1];
            float ox = crow[h * 24 + lp * 2];
            float oy = crow[h * 24 + lp * 2 + 1];
            float x = rx * fW + ox - 0.5f;
            float y = ry * fW + oy - 0.5f;
            float x0f = floorf(x), y0f = floorf(y);
            float wx = x - x0f, wy = y - y0f;
            int x0 = (int)x0f, y0 = (int)y0f;
            int x1 = x0 + 1, y1 = y0 + 1;
            float vx0 = (x0 >= 0 && x0 < Wl) ? 1.f : 0.f;
            float vx1 = (x1 >= 0 && x1 < Wl) ? 1.f : 0.f;
            float vy0 = (y0 >= 0 && y0 < Wl) ? 1.f : 0.f;   // square levels
            float vy1 = (y1 >= 0 && y1 < Wl) ? 1.f : 0.f;
            int yc0 = min(max(y0, 0), Wl - 1);
            int yc1 = min(max(y1, 0), Wl - 1);
            int px = min(max(x0, 0), Wl - 2);
            float wxl = (1.f - wx) * vx0;    // weight of corner x0
            float wxh = wx * vx1;            // weight of corner x1
            float wA, wB;
            if (px == x0)      { wA = wxl; wB = wxh; }   // interior
            else if (px == x1) { wA = wxh; wB = 0.f; }   // x0 == -1
            else               { wA = 0.f; wB = wxl; }   // x0 == Wl-1
            float wy0v = aw * (1.f - wy) * vy0;
            float wy1v = aw * wy * vy1;
            int st = (l == 0) ? 0 : ((l == 1) ? 4096 : 5120);
            int rowbase = b * SEQ + st;
            s_idx[q][h][lp] = make_int2((rowbase + yc0 * Wl + px) * 32,
                                        (rowbase + yc1 * Wl + px) * 32);
            s_w[q][h][lp] = make_float4(wA * wy0v, wB * wy0v,
                                        wA * wy1v, wB * wy1v);
        }
    }
    __syncthreads();

    // ---- phase 2: x-pair gathers + packed FMA ----
    int wave = tid >> 6, lane = tid & 63;
    int q = wave;
    int bq = bq0 + q;
    int h = lane >> 3;
    int d8 = lane & 7;
    int part = d8 >> 2;                  // 0: x=px, 1: x=px+1
    int c4 = d8 & 3;                     // channel quad (8 ch)
    const ushort* vb = value + (size_t)h * ((size_t)MTOT * 32)
                       + part * 32 + c4 * 8;

    f32x2 acc[4] = {{0.f, 0.f}, {0.f, 0.f}, {0.f, 0.f}, {0.f, 0.f}};
    #pragma unroll
    for (int lp = 0; lp < 12; lp++) {
        int2 ii = s_idx[q][h][lp];
        float4 ww = s_w[q][h][lp];
        float w0 = part ? ww.y : ww.x;
        float w1 = part ? ww.w : ww.z;
        uint4 u0 = *(const uint4*)(vb + ii.x);
        uint4 u1 = *(const uint4*)(vb + ii.y);
        fma8p(acc, w0, u0);
        fma8p(acc, w1, u1);
    }

    // combine the two x-parts (lane ^ 4 flips `part`, same h/c4)
    #pragma unroll
    for (int i = 0; i < 4; i++) {
        acc[i][0] += __shfl_xor(acc[i][0], 4);
        acc[i][1] += __shfl_xor(acc[i][1], 4);
    }
    if (part == 0) {
        bf16x8 o;
        o[0] = (short)f2b(acc[0][0]); o[1] = (short)f2b(acc[0][1]);
        o[2] = (short)f2b(acc[1][0]); o[3] = (short)f2b(acc[1][1]);
        o[4] = (short)f2b(acc[2][0]); o[5] = (short)f2b(acc[2][1]);
        o[6] = (short)f2b(acc[3][0]); o[7] = (short)f2b(acc[3][1]);
        *(bf16x8*)(out + (size_t)bq * 256 + h * 32 + c4 * 8) = o;
    }
}

// ---------------------------------------------------------------------------
extern "C" void kernel_launch(void* const* d_in, const int* in_sizes, int n_in,
                              void* d_out, int out_size, void* d_ws, size_t ws_size,
                              hipStream_t stream) {
    const float* hidden = (const float*)d_in[0];
    const float* pos    = (const float*)d_in[1];
    const float* refp   = (const float*)d_in[2];
    const float* Wv     = (const float*)d_in[3];
    const float* bv     = (const float*)d_in[4];
    const float* Wo     = (const float*)d_in[5];
    const float* bo     = (const float*)d_in[6];
    const float* Wa     = (const float*)d_in[7];
    const float* ba     = (const float*)d_in[8];
    const float* Wout   = (const float*)d_in[9];
    const float* bout   = (const float*)d_in[10];

    float* out      = (float*)d_out;                       // (B,SEQ,256)
    float* attn_out = out + (size_t)BB * SEQ * DD;         // (B,SEQ,NH,NL,NP)

    const size_t BSD = (size_t)BB * SEQ * DD;              // 5,505,024
    char* w = (char*)d_ws;
    ushort* value_bf = (ushort*)w;  w += BSD * 2;                 // bf16 value (head-major)
    float*  comb     = (float*)w;   w += (size_t)MTOT * 288 * 4;  // off|logits
    ushort* sampb    = (ushort*)w;  w += BSD * 2;                 // bf16 sampled
    ushort* hb       = (ushort*)w;  w += BSD * 2;                 // bf16 hidden
    ushort* hsb      = (ushort*)w;  w += BSD * 2;                 // bf16 hidden+pos
    ushort* Wt       = (ushort*)w;  w += (size_t)800 * 256 * 2;   // bf16 weights^T
    float*  bcomb    = (float*)w;                                 // 288 bias

    // 1. fused prep: weights transpose + activation bf16 conversion
    {
        int n4 = (int)(BSD / 4);
        prep_all<<<801 + 2048, 256, 0, stream>>>(hidden, pos, Wv, Wo, Wa, Wout,
                                                 bo, ba, (ushort4*)hb, (ushort4*)hsb,
                                                 Wt, bcomb, n4);
    }

    const ushort* Wv_t    = Wt;
    const ushort* Wcomb_t = Wt + (size_t)256 * 256;   // rows: 192 Wo + 96 Wa
    const ushort* Wout_t  = Wt + (size_t)544 * 256;

    // 2. fused value+comb GEMMs (840 blocks for grid fill)
    gemm_dual<<<840, 256, 0, stream>>>(hb, hsb, Wv_t, Wcomb_t, bv, bcomb,
                                       value_bf, comb);

    // 3. fused softmax + deformable sampling -> attn_out + sampled bf16
    msda_sample_v12<<<MTOT / 2, 128, 0, stream>>>(value_bf, comb, refp,
                                                  attn_out, sampb);

    // 4. out = sampled @ Wout + bout -> d_out (BN=64: 672 blocks)
    {
        dim3 grid(DD / 64, MTOT / 128);
        gemm_out<<<grid, 256, 0, stream>>>(sampb, Wout_t, bout, out);
    }
}